// Round 1
// baseline (436.367 us; speedup 1.0000x reference)
//
#include <hip/hip_runtime.h>

// HDP-HMM forward-backward, exact-semantics parallel decomposition.
//
// Key observation: reference normalizes by (sum + 1e-10) where sum ~ exp(em) ~ 1e-13,
// so the recursion is NOT scale-invariant. Split into:
//   direction (scale-free filter, chunk-parallel with warm-up; P>0 => Birkhoff contraction)
//   norm s_t = z/(z+eps), z = s_{t-1}*m_t  => Mobius maps, composed per chunk as 2x2
//   lower-triangular matrices (a,0;c,d), combined by a small scan kernel, replayed per chunk.
// alpha_t = u_t * s_{t-1}/(z+eps) reproduces the reference division exactly (up to ulps).

namespace {
constexpr int Tn = 262144;
constexpr int Kn = 20;
constexpr int Fn = 16;
constexpr int Ln = 256;              // chunk body length
constexpr int Wn = 192;              // warm-up steps
constexpr int NC = Tn / Ln;          // 1024 chunks per direction
constexpr float EPSF = 1e-10f;

// ws layout (floats); total ~535,608 floats = 2.15 MB
constexpr size_t OFF_MF   = 0;                      // m_t forward  [Tn]
constexpr size_t OFF_MB   = (size_t)Tn;             // m'_t backward [Tn]
constexpr size_t OFF_MATF = 2*(size_t)Tn;           // fwd chunk Mobius [NC][4]
constexpr size_t OFF_MATB = OFF_MATF + 4*(size_t)NC;// bwd chunk Mobius (slot-reversed) [NC][4]
constexpr size_t OFF_SF   = OFF_MATB + 4*(size_t)NC;// s entering fwd chunk c [NC]
constexpr size_t OFF_SB   = OFF_SF + NC;            // s entering bwd slot [NC]
constexpr size_t OFF_P    = OFF_SB + NC;            // P row-major [Kn*Kn]
constexpr size_t OFF_W    = OFF_P + Kn*Kn;          // stick-breaking w [Kn]
constexpr size_t OFF_CK   = OFF_W + Kn;             // emission const per k [Kn]
constexpr size_t OFF_MV   = OFF_CK + Kn;            // means*inv [Kn*Fn]
constexpr size_t OFF_IV   = OFF_MV + Kn*Fn;         // inv var   [Kn*Fn]
}

__device__ __forceinline__ float groupReduce32(float v) {
#pragma unroll
  for (int off = 16; off >= 1; off >>= 1)
    v += __shfl_xor(v, off, 32);
  return v;
}

__global__ __launch_bounds__(64) void prep_kernel(
    const float* beta_logits, const float* pi_logits,
    const float* means, const float* log_vars, float* ws)
{
  int k = threadIdx.x;
  if (k < Kn) {
    // softmax row k (with max subtraction, as jax.nn.softmax)
    float row[Kn];
    float mx = -1e30f;
#pragma unroll
    for (int j = 0; j < Kn; ++j) { row[j] = pi_logits[k*Kn + j]; mx = fmaxf(mx, row[j]); }
    float s = 0.f;
#pragma unroll
    for (int j = 0; j < Kn; ++j) { row[j] = expf(row[j] - mx); s += row[j]; }
    float invs = 1.0f / s;
#pragma unroll
    for (int j = 0; j < Kn; ++j) ws[OFF_P + k*Kn + j] = row[j] * invs;
    // emission constants
    float ck = 0.f;
#pragma unroll
    for (int f = 0; f < Fn; ++f) {
      float lv  = log_vars[k*Fn + f];
      float var = expf(lv) + 1e-6f;
      float iv  = 1.0f / var;
      float mu  = means[k*Fn + f];
      ws[OFF_MV + k*Fn + f] = mu * iv;
      ws[OFF_IV + k*Fn + f] = iv;
      ck += mu*mu*iv + logf(6.2831853071795864f * var);
    }
    ws[OFF_CK + k] = ck;
  } else if (k == Kn) {
    // stick-breaking: w_k = sigmoid(l_k) * prod_{i<k}(1 - sigmoid(l_i))
    float cp = 1.f;
#pragma unroll
    for (int i = 0; i < Kn; ++i) {
      float b = 1.0f / (1.0f + expf(-beta_logits[i]));
      ws[OFF_W + i] = b * cp;
      cp *= (1.0f - b);
    }
  }
}

// One wave = 2 chunk-groups (lanes 0..19 and 32..51 active). Blocks [0,NC/2) forward,
// [NC/2,NC) backward. Directions stored unnormalized (u) into d_out; per-step norm
// multiplier m recorded to ws; per-chunk Mobius (a,c,d) accumulated in registers.
__global__ __launch_bounds__(64) void scan_kernel(
    const float* __restrict__ obs, float* ws, float* out)
{
  __shared__ float xsh[2][32];
  const int tid = threadIdx.x;
  const int g   = tid >> 5;
  const int jj  = tid & 31;
  const bool act = (jj < Kn);
  const bool isF = (blockIdx.x < (NC/2));
  const int c = isF ? ((int)blockIdx.x*2 + g) : (((int)blockIdx.x - NC/2)*2 + g);

  // per-lane constants
  float Pv[Kn];          // fwd: column jj of P ; bwd: row jj of P
  float mv[Fn], iv[Fn];
  float ck = 0.f;
  if (act) {
#pragma unroll
    for (int k = 0; k < Kn; ++k)
      Pv[k] = isF ? ws[OFF_P + k*Kn + jj] : ws[OFF_P + jj*Kn + k];
#pragma unroll
    for (int f = 0; f < Fn; ++f) {
      mv[f] = ws[OFF_MV + jj*Fn + f];
      iv[f] = ws[OFF_IV + jj*Fn + f];
    }
    ck = ws[OFF_CK + jj];
  } else {
#pragma unroll
    for (int k = 0; k < Kn; ++k) Pv[k] = 0.f;
#pragma unroll
    for (int f = 0; f < Fn; ++f) { mv[f] = 0.f; iv[f] = 0.f; }
  }

  float Ma = 1.f, Mc = 0.f, Md = 1.f;   // chunk Mobius, identity
  float* mArr = ws + (isF ? OFF_MF : OFF_MB);
  float* uOut = out + (isF ? (size_t)0 : (size_t)Tn * Kn);

  auto emexp = [&](int t) -> float {
    const float4* o4 = (const float4*)(obs + (size_t)t * Fn);
    float4 A = o4[0], B = o4[1], C4 = o4[2], D = o4[3];
    float o[16] = {A.x,A.y,A.z,A.w, B.x,B.y,B.z,B.w,
                   C4.x,C4.y,C4.z,C4.w, D.x,D.y,D.z,D.w};
    float s1a=0.f, s1b=0.f, s2a=0.f, s2b=0.f;
#pragma unroll
    for (int f = 0; f < Fn; f += 2) {
      s1a = fmaf(o[f]*o[f],     iv[f],   s1a);
      s1b = fmaf(o[f+1]*o[f+1], iv[f+1], s1b);
      s2a = fmaf(o[f],   mv[f],   s2a);
      s2b = fmaf(o[f+1], mv[f+1], s2b);
    }
    float em = -0.5f * ((s1a + s1b) - 2.0f*(s2a + s2b) + ck);
    return __expf(em);
  };
  auto mobius = [&](float m) {
    float na = m * Ma;
    float nc = fmaf(EPSF, Mc, na);
    float nd = EPSF * Md;
    float mx = fmaxf(nc, nd);          // na <= nc always (nonneg)
    float lam = (mx > 0.f) ? (1.0f/mx) : 1.0f;
    Ma = na*lam; Mc = nc*lam; Md = nd*lam;
  };
  auto matvec = [&]() -> float {
    float a0=0.f, a1=0.f, a2=0.f, a3=0.f;
#pragma unroll
    for (int k = 0; k < Kn; k += 4) {
      a0 = fmaf(xsh[g][k+0], Pv[k+0], a0);
      a1 = fmaf(xsh[g][k+1], Pv[k+1], a1);
      a2 = fmaf(xsh[g][k+2], Pv[k+2], a2);
      a3 = fmaf(xsh[g][k+3], Pv[k+3], a3);
    }
    return (a0+a1) + (a2+a3);
  };

  if (isF) {
    const int bodyStart = c * Ln;
    const int tend = bodyStart + Ln - 1;
    const int t0 = (c == 0) ? 0 : (bodyStart - Wn);
    float wj = act ? ws[OFF_W + jj] : 0.f;
    float u, im, m;
    {
      float e = emexp(t0);
      u = (c == 0) ? (wj * e) : (act ? 0.05f * e : 0.f);
    }
    m = groupReduce32(u);
    if (t0 >= bodyStart) {            // only chunk 0
      if (jj == 0) mArr[t0] = m;
      mobius(m);
      if (act) uOut[(size_t)t0 * Kn + jj] = u;
    }
    if (m < 1e-35f) { u = act ? 0.05f : 0.f; im = 1.0f; } else im = 1.0f / m;

    for (int t = t0 + 1; t <= tend; ++t) {
      xsh[g][jj] = u;
      float acc = matvec();
      float e = emexp(t);
      u = acc * (e * im);
      m = groupReduce32(u);
      if (t >= bodyStart) {
        if (jj == 0) mArr[t] = m;
        mobius(m);
        if (act) uOut[(size_t)t * Kn + jj] = u;
      }
      if (m < 1e-35f) { u = act ? 0.05f : 0.f; im = 1.0f; } else im = 1.0f / m;
    }
    if (jj == 0) {
      float4* M4 = (float4*)(ws + OFF_MATF);
      M4[c] = make_float4(Ma, Mc, Md, 0.f);
    }
  } else {
    const int bodyStart = c * Ln;
    const int top = bodyStart + Ln - 1;
    int r0 = top + Wn; if (r0 > Tn - 1) r0 = Tn - 1;   // r0==Tn-1 => exact init (b_T = ones)
    float u = act ? 0.05f : 0.f;   // uniform direction
    float im = 1.0f, m;
    for (int r = r0 - 1; r >= bodyStart; --r) {
      const int src = r + 1;
      float e = emexp(src);
      xsh[g][jj] = u * e;
      float acc = matvec();
      u = acc * im;
      m = groupReduce32(u);          // = m'_{src} = ||P(b_hat .* e_src)||_1
      if (r <= top) {
        if (jj == 0) mArr[src] = m;
        mobius(m);
        if (act) uOut[(size_t)r * Kn + jj] = u;
      }
      if (m < 1e-35f) { u = act ? 0.05f : 0.f; im = 1.0f; } else im = 1.0f / m;
    }
    if (jj == 0) {
      float4* M4 = (float4*)(ws + OFF_MATB);
      M4[NC - 1 - c] = make_float4(Ma, Mc, Md, 0.f);  // slot-reversed: application order
    }
  }
}

// One block, 2 waves: wave0 forward (s0=1), wave1 backward (s0=20, slots already in
// application order). Non-commutative Hillis-Steele scan of Mobius maps across 64 lanes.
__global__ __launch_bounds__(128) void combine_kernel(float* ws)
{
  const int wid  = threadIdx.x >> 6;
  const int lane = threadIdx.x & 63;
  const float4* M4 = (const float4*)(ws + (wid == 0 ? OFF_MATF : OFF_MATB));
  float* sArr = ws + (wid == 0 ? OFF_SF : OFF_SB);
  const float s0 = (wid == 0) ? 1.0f : 20.0f;
  constexpr int PG = NC / 64;   // 16 chunks per lane

  float a = 1.f, cc = 0.f, d = 1.f;   // composite of my 16, in order
  for (int i = 0; i < PG; ++i) {
    float4 mm = M4[lane*PG + i];
    float na = mm.x * a;
    float nc = fmaf(mm.y, a, mm.z * cc);
    float nd = mm.z * d;
    float mx = fmaxf(na, fmaxf(nc, nd));
    float lam = (mx > 0.f) ? (1.0f/mx) : 1.0f;
    a = na*lam; cc = nc*lam; d = nd*lam;
  }
  float ia = a, ic = cc, id = d;      // inclusive scan (lane composes after lower lanes)
  for (int off = 1; off < 64; off <<= 1) {
    float pa = __shfl_up(ia, off, 64);
    float pc = __shfl_up(ic, off, 64);
    float pd = __shfl_up(id, off, 64);
    if (lane >= off) {
      float na = ia * pa;
      float nc = fmaf(ic, pa, id * pc);
      float nd = id * pd;
      float mx = fmaxf(na, fmaxf(nc, nd));
      float lam = (mx > 0.f) ? (1.0f/mx) : 1.0f;
      ia = na*lam; ic = nc*lam; id = nd*lam;
    }
  }
  float ea = __shfl_up(ia, 1, 64);
  float ec = __shfl_up(ic, 1, 64);
  float ed = __shfl_up(id, 1, 64);
  if (lane == 0) { ea = 1.f; ec = 0.f; ed = 1.f; }
  float s;
  { float num = ea * s0; float den = fmaf(ec, s0, ed);
    s = (den > 0.f) ? num/den : 0.f; }
  for (int i = 0; i < PG; ++i) {
    sArr[lane*PG + i] = s;            // s ENTERING this slot
    float4 mm = M4[lane*PG + i];
    float num = mm.x * s; float den = fmaf(mm.y, s, mm.z);
    s = (den > 0.f) ? num/den : 0.f;
  }
}

// Replay s per chunk and scale stored directions in place:
//   val = u_j * s_prev / (z + eps),  z = s_prev * m_t  (== reference x/(x.sum()+1e-10))
__global__ __launch_bounds__(64) void scale_kernel(float* ws, float* out)
{
  const int tid = threadIdx.x;
  const int g   = tid >> 5;
  const int jj  = tid & 31;
  const bool act = (jj < Kn);
  const bool isF = (blockIdx.x < (NC/2));
  const int c = isF ? ((int)blockIdx.x*2 + g) : (((int)blockIdx.x - NC/2)*2 + g);

  if (isF) {
    const float* mArr = ws + OFF_MF;
    float* A = out;
    float s = ws[OFF_SF + c];
    const int t0 = c * Ln;
    for (int t = t0; t < t0 + Ln; ++t) {
      float mm = mArr[t];
      float z = s * mm;
      float den = z + EPSF;
      float inv = 1.0f / den;
      float scale = s * inv;
      float val = 0.f;
      if (act) {
        size_t idx = (size_t)t * Kn + jj;
        val = A[idx] * scale;
        A[idx] = val;
      }
      s = z * inv;
      if (t == Tn - 1) {
        float tot = groupReduce32(val);
        if (jj == 0) out[(size_t)2 * Tn * Kn] = logf(tot + EPSF);
      }
    }
  } else {
    const float* mArr = ws + OFF_MB;
    float* B = out + (size_t)Tn * Kn;
    const int slot = NC - 1 - c;
    float s = ws[OFF_SB + slot];
    const int bodyStart = c * Ln;
    const int top = bodyStart + Ln - 1;
    for (int r = top; r >= bodyStart; --r) {
      if (r == Tn - 1) {                      // beta[T-1] = ones exactly
        if (act) B[(size_t)r * Kn + jj] = 1.0f;
        continue;
      }
      float mm = mArr[r + 1];
      float z = s * mm;
      float den = z + EPSF;
      float inv = 1.0f / den;
      float scale = s * inv;
      if (act) {
        size_t idx = (size_t)r * Kn + jj;
        B[idx] = B[idx] * scale;
      }
      s = z * inv;
    }
  }
}

extern "C" void kernel_launch(void* const* d_in, const int* in_sizes, int n_in,
                              void* d_out, int out_size, void* d_ws, size_t ws_size,
                              hipStream_t stream) {
  const float* obs         = (const float*)d_in[0];
  const float* beta_logits = (const float*)d_in[1];
  const float* pi_logits   = (const float*)d_in[2];
  const float* means       = (const float*)d_in[3];
  const float* log_vars    = (const float*)d_in[4];
  float* out = (float*)d_out;
  float* ws  = (float*)d_ws;   // needs ~2.15 MB

  hipLaunchKernelGGL(prep_kernel, dim3(1), dim3(64), 0, stream,
                     beta_logits, pi_logits, means, log_vars, ws);
  hipLaunchKernelGGL(scan_kernel, dim3(NC), dim3(64), 0, stream, obs, ws, out);
  hipLaunchKernelGGL(combine_kernel, dim3(1), dim3(128), 0, stream, ws);
  hipLaunchKernelGGL(scale_kernel, dim3(NC), dim3(64), 0, stream, ws, out);
}

// Round 2
// 303.225 us; speedup vs baseline: 1.4391x; 1.4391x over previous
//
#include <hip/hip_runtime.h>

// HDP-HMM forward-backward, exact-semantics parallel decomposition. R2:
//  - emission probs E=exp(em) precomputed in a parallel kernel (was inline in the serial scan)
//  - late (one-step-stale) normalization: reduce+rcp off the loop-carried critical path
//  - Ln=128/Wn=128 -> 256 steps/chunk, 2048 waves (2/SIMD)
//  - fallback to the R1 pipeline if ws_size < ~25.3 MB

namespace {
constexpr int Tn = 262144;
constexpr int Kn = 20;
constexpr int Fn = 16;
constexpr float EPSF = 1e-10f;
constexpr float TINY = 1e-35f;

// ---- new-path config ----
constexpr int Ln2 = 128;
constexpr int Wn2 = 128;
constexpr int NC2 = Tn / Ln2;          // 2048 chunks per direction

// ws layout (floats), new path
constexpr size_t OFF_P    = 0;                      // P row-major [400]
constexpr size_t OFF_W    = 400;                    // stick weights [20]
constexpr size_t OFF_CK   = 420;                    // emission const [20]
constexpr size_t OFF_MV   = 440;                    // means*inv [320] (kept for fallback-compat noop)
constexpr size_t OFF_IV   = 760;                    // inv var [320]
constexpr size_t OFF_MVIV = 1080;                   // float2 (mv,iv) [640]
constexpr size_t OFF_E    = 1728;                   // E[t*20+k] + 64 pad
constexpr size_t OFF_MSF  = OFF_E + (size_t)Tn*20 + 64;      // float2[Tn] fwd (m, 1/sigma)
constexpr size_t OFF_MSB  = OFF_MSF + 2*(size_t)Tn;          // float2[Tn] bwd
constexpr size_t OFF_MATF = OFF_MSB + 2*(size_t)Tn;          // [NC2][4]
constexpr size_t OFF_MATB = OFF_MATF + 4*(size_t)NC2;
constexpr size_t OFF_SF   = OFF_MATB + 4*(size_t)NC2;        // [NC2]
constexpr size_t OFF_SB   = OFF_SF + NC2;                    // [NC2]
constexpr size_t OFF_END  = OFF_SB + NC2;
}

#if __has_builtin(__builtin_amdgcn_rcpf)
#define FRCP(x) __builtin_amdgcn_rcpf(x)
#else
#define FRCP(x) (1.0f/(x))
#endif

__device__ __forceinline__ float groupReduce32(float v) {
#pragma unroll
  for (int off = 16; off >= 1; off >>= 1)
    v += __shfl_xor(v, off, 32);
  return v;
}

// ============================ shared prep ============================
__global__ __launch_bounds__(64) void prep_kernel(
    const float* beta_logits, const float* pi_logits,
    const float* means, const float* log_vars, float* ws)
{
  int k = threadIdx.x;
  if (k < Kn) {
    float row[Kn];
    float mx = -1e30f;
#pragma unroll
    for (int j = 0; j < Kn; ++j) { row[j] = pi_logits[k*Kn + j]; mx = fmaxf(mx, row[j]); }
    float s = 0.f;
#pragma unroll
    for (int j = 0; j < Kn; ++j) { row[j] = expf(row[j] - mx); s += row[j]; }
    float invs = 1.0f / s;
#pragma unroll
    for (int j = 0; j < Kn; ++j) ws[OFF_P + k*Kn + j] = row[j] * invs;
    float ck = 0.f;
#pragma unroll
    for (int f = 0; f < Fn; ++f) {
      float lv  = log_vars[k*Fn + f];
      float var = expf(lv) + 1e-6f;
      float iv  = 1.0f / var;
      float mu  = means[k*Fn + f];
      ws[OFF_MV + k*Fn + f] = mu * iv;
      ws[OFF_IV + k*Fn + f] = iv;
      ((float2*)(ws + OFF_MVIV))[k*Fn + f] = make_float2(mu * iv, iv);
      ck += mu*mu*iv + logf(6.2831853071795864f * var);
    }
    ws[OFF_CK + k] = ck;
  } else if (k == Kn) {
    float cp = 1.f;
#pragma unroll
    for (int i = 0; i < Kn; ++i) {
      float b = 1.0f / (1.0f + expf(-beta_logits[i]));
      ws[OFF_W + i] = b * cp;
      cp *= (1.0f - b);
    }
  }
}

// ============================ new path ============================
__global__ __launch_bounds__(256) void emis_kernel(const float* __restrict__ obs, float* ws)
{
  int gid = blockIdx.x * 256 + threadIdx.x;
  if (gid >= Tn * Kn) return;
  unsigned t = (unsigned)gid / 20u;
  int k = gid - (int)t * 20;
  const float2* mviv = (const float2*)(ws + OFF_MVIV) + k*Fn;
  const float* o = obs + (size_t)t * Fn;
  float ck = ws[OFF_CK + k];
  float s1 = 0.f, s2 = 0.f;
#pragma unroll
  for (int f = 0; f < Fn; ++f) {
    float2 c2 = mviv[f];
    float ov = o[f];
    s1 = fmaf(c2.y * ov, ov, s1);
    s2 = fmaf(c2.x, ov, s2);
  }
  float em = fmaf(-0.5f, s1 + ck, s2);
  ws[OFF_E + gid] = __expf(em);
}

__global__ __launch_bounds__(64) void scan2_kernel(float* ws, float* out)
{
  __shared__ float4 xsh4[2][8];
  const int tid = threadIdx.x;
  const int g   = tid >> 5;
  const int jj  = tid & 31;
  const bool act = (jj < Kn);
  const bool isF = (blockIdx.x < (NC2/2));
  const int c = isF ? ((int)blockIdx.x*2 + g) : (((int)blockIdx.x - NC2/2)*2 + g);
  const float* E = ws + OFF_E;
  float* xg = (float*)&xsh4[g][0];

  float Pv[Kn];
#pragma unroll
  for (int k = 0; k < Kn; ++k)
    Pv[k] = act ? (isF ? ws[OFF_P + k*Kn + jj] : ws[OFF_P + jj*Kn + k]) : 0.f;

  float Ma = 1.f, Mc = 0.f, Md = 1.f;
  float2* msig = (float2*)(ws + (isF ? OFF_MSF : OFF_MSB));
  float* uOut = out + (isF ? (size_t)0 : (size_t)Tn * Kn);

  auto mobius = [&](float m) {
    float na = m * Ma;
    float nc = fmaf(EPSF, Mc, na);
    float nd = EPSF * Md;
    float mx = fmaxf(nc, nd);
    float lam = (mx > 0.f) ? FRCP(mx) : 1.0f;
    Ma = na*lam; Mc = nc*lam; Md = nd*lam;
  };
  auto matvec = [&]() -> float {
    float4 x0 = xsh4[g][0], x1 = xsh4[g][1], x2 = xsh4[g][2],
           x3 = xsh4[g][3], x4 = xsh4[g][4];
    float a0 = x0.x*Pv[0], a1 = x0.y*Pv[1], a2 = x0.z*Pv[2], a3 = x0.w*Pv[3];
    a0 = fmaf(x1.x, Pv[4], a0); a1 = fmaf(x1.y, Pv[5], a1);
    a2 = fmaf(x1.z, Pv[6], a2); a3 = fmaf(x1.w, Pv[7], a3);
    a0 = fmaf(x2.x, Pv[8], a0); a1 = fmaf(x2.y, Pv[9], a1);
    a2 = fmaf(x2.z, Pv[10], a2); a3 = fmaf(x2.w, Pv[11], a3);
    a0 = fmaf(x3.x, Pv[12], a0); a1 = fmaf(x3.y, Pv[13], a1);
    a2 = fmaf(x3.z, Pv[14], a2); a3 = fmaf(x3.w, Pv[15], a3);
    a0 = fmaf(x4.x, Pv[16], a0); a1 = fmaf(x4.y, Pv[17], a1);
    a2 = fmaf(x4.z, Pv[18], a2); a3 = fmaf(x4.w, Pv[19], a3);
    return (a0+a1) + (a2+a3);
  };

  if (isF) {
    const int bodyStart = c * Ln2;
    const int tend = bodyStart + Ln2 - 1;
    const int t0 = (c == 0) ? 0 : (bodyStart - Wn2);
    float wj = act ? ws[OFF_W + jj] : 0.f;
    float e0 = E[t0*20 + jj];
    float v = act ? ((c == 0) ? wj * e0 : 0.05f * e0) : 0.f;
    float sv = groupReduce32(v);
    float m = sv;                               // A_prev = 1
    float iV = (sv > TINY) ? FRCP(sv) : 1.0f;
    if (sv <= TINY) v = act ? 0.05f : 0.f;
    if (c == 0) {
      if (jj == 0) msig[0] = make_float2(m, iV);
      mobius(m);
      if (act) uOut[jj] = v;
    }
    float A = m * iV;
    float rho = (m > TINY) ? FRCP(m) : 1.0f;
    float e1 = E[(t0+1)*20 + jj];
    float e2 = E[(t0+2)*20 + jj];

#define FWD_STEP(REC)                                                     \
    {                                                                     \
      xg[jj] = v;                                                         \
      float acc = matvec();                                               \
      float er = e1 * rho;                                                \
      e1 = e2; e2 = E[(t+2)*20 + jj];                                     \
      v = acc * er;                                                       \
      float sv2 = groupReduce32(v);                                       \
      m = sv2 * A;                                                        \
      float iVn = (sv2 > TINY) ? FRCP(sv2) : 1.0f;                        \
      if (sv2 <= TINY) v = act ? 0.05f : 0.f;                             \
      if (REC) {                                                          \
        if (jj == 0) msig[t] = make_float2(m, iVn);                       \
        mobius(m);                                                        \
        if (act) uOut[(size_t)t*Kn + jj] = v;                             \
      }                                                                   \
      A = m * iVn;                                                        \
      rho = (m > TINY) ? FRCP(m) : 1.0f;                                  \
    }

    for (int t = t0 + 1; t < bodyStart; ++t) FWD_STEP(false)
    const int bstart2 = (c == 0) ? 1 : bodyStart;
    for (int t = bstart2; t <= tend; ++t) FWD_STEP(true)
#undef FWD_STEP
    if (jj == 0) ((float4*)(ws + OFF_MATF))[c] = make_float4(Ma, Mc, Md, 0.f);
  } else {
    const int bodyStart = c * Ln2;
    const int top = bodyStart + Ln2 - 1;
    int r0 = top + Wn2; if (r0 > Tn - 1) r0 = Tn - 1;
    float v = act ? 0.05f : 0.f;
    float sv = groupReduce32(v);                 // ~1.0
    float iV = (sv > TINY) ? FRCP(sv) : 1.0f;
    float A = iV;                                // m_prev = 1 convention
    float rho = 1.0f, m;
    float e1 = E[r0*20 + jj];
    float e2 = E[(r0-1)*20 + jj];

#define BWD_STEP(REC)                                                     \
    {                                                                     \
      xg[jj] = v * e1;                                                    \
      float acc = matvec();                                               \
      v = acc * rho;                                                      \
      e1 = e2; e2 = E[(r-1)*20 + jj];                                     \
      float sv2 = groupReduce32(v);                                       \
      m = sv2 * A;                                                        \
      float iVn = (sv2 > TINY) ? FRCP(sv2) : 1.0f;                        \
      if (sv2 <= TINY) v = act ? 0.05f : 0.f;                             \
      if (REC) {                                                          \
        if (jj == 0) msig[r+1] = make_float2(m, iVn);                     \
        mobius(m);                                                        \
        if (act) uOut[(size_t)r*Kn + jj] = v;                             \
      }                                                                   \
      A = m * iVn;                                                        \
      rho = (m > TINY) ? FRCP(m) : 1.0f;                                  \
    }

    for (int r = r0 - 1; r > top; --r) BWD_STEP(false)
    int rb = (r0 - 1 < top) ? (r0 - 1) : top;
    for (int r = rb; r >= bodyStart; --r) BWD_STEP(true)
#undef BWD_STEP
    if (jj == 0) ((float4*)(ws + OFF_MATB))[NC2 - 1 - c] = make_float4(Ma, Mc, Md, 0.f);
  }
}

__global__ __launch_bounds__(128) void combine2_kernel(float* ws, float* out)
{
  const int wid  = threadIdx.x >> 6;
  const int lane = threadIdx.x & 63;
  const float4* M4 = (const float4*)(ws + (wid == 0 ? OFF_MATF : OFF_MATB));
  float* sArr = ws + (wid == 0 ? OFF_SF : OFF_SB);
  const float s0 = (wid == 0) ? 1.0f : 20.0f;
  constexpr int PG = NC2 / 64;   // 32

  float a = 1.f, cc = 0.f, d = 1.f;
  for (int i = 0; i < PG; ++i) {
    float4 mm = M4[lane*PG + i];
    float na = mm.x * a;
    float nc = fmaf(mm.y, a, mm.z * cc);
    float nd = mm.z * d;
    float mx = fmaxf(na, fmaxf(nc, nd));
    float lam = (mx > 0.f) ? (1.0f/mx) : 1.0f;
    a = na*lam; cc = nc*lam; d = nd*lam;
  }
  float ia = a, ic = cc, id = d;
  for (int off = 1; off < 64; off <<= 1) {
    float pa = __shfl_up(ia, off, 64);
    float pc = __shfl_up(ic, off, 64);
    float pd = __shfl_up(id, off, 64);
    if (lane >= off) {
      float na = ia * pa;
      float nc = fmaf(ic, pa, id * pc);
      float nd = id * pd;
      float mx = fmaxf(na, fmaxf(nc, nd));
      float lam = (mx > 0.f) ? (1.0f/mx) : 1.0f;
      ia = na*lam; ic = nc*lam; id = nd*lam;
    }
  }
  if (wid == 0 && lane == 63) {
    float den = fmaf(ic, s0, id);
    float sfin = (den > 0.f) ? (ia * s0)/den : 0.f;
    out[(size_t)2 * Tn * Kn] = logf(sfin + EPSF);
  }
  float ea = __shfl_up(ia, 1, 64);
  float ec = __shfl_up(ic, 1, 64);
  float ed = __shfl_up(id, 1, 64);
  if (lane == 0) { ea = 1.f; ec = 0.f; ed = 1.f; }
  float s;
  { float num = ea * s0; float den = fmaf(ec, s0, ed);
    s = (den > 0.f) ? num/den : 0.f; }
  for (int i = 0; i < PG; ++i) {
    sArr[lane*PG + i] = s;
    float4 mm = M4[lane*PG + i];
    float num = mm.x * s; float den = fmaf(mm.y, s, mm.z);
    s = (den > 0.f) ? num/den : 0.f;
  }
}

__global__ __launch_bounds__(64) void scale2_kernel(float* ws, float* out)
{
  const int tid = threadIdx.x;
  const int g   = tid >> 5;
  const int jj  = tid & 31;
  const bool act = (jj < Kn);
  const bool isF = (blockIdx.x < (NC2/2));
  const int c = isF ? ((int)blockIdx.x*2 + g) : (((int)blockIdx.x - NC2/2)*2 + g);

  if (isF) {
    const float2* msig = (const float2*)(ws + OFF_MSF);
    float* A = out;
    float s = ws[OFF_SF + c];
    const int t0 = c * Ln2;
    for (int t = t0; t < t0 + Ln2; ++t) {
      float2 p = msig[t];
      float z = s * p.x;
      float den = z + EPSF;
      float sn = z / den;
      if (act) {
        size_t idx = (size_t)t * Kn + jj;
        A[idx] = A[idx] * (sn * p.y);
      }
      s = sn;
    }
  } else {
    const float2* msig = (const float2*)(ws + OFF_MSB);
    float* B = out + (size_t)Tn * Kn;
    const int slot = NC2 - 1 - c;
    float s = ws[OFF_SB + slot];
    const int bodyStart = c * Ln2;
    const int top = bodyStart + Ln2 - 1;
    for (int r = top; r >= bodyStart; --r) {
      if (r == Tn - 1) {
        if (act) B[(size_t)r * Kn + jj] = 1.0f;
        continue;
      }
      float2 p = msig[r + 1];
      float z = s * p.x;
      float den = z + EPSF;
      float sn = z / den;
      if (act) {
        size_t idx = (size_t)r * Kn + jj;
        B[idx] = B[idx] * (sn * p.y);
      }
      s = sn;
    }
  }
}

// ============================ fallback (R1, verbatim semantics) ============================
namespace v1 {
constexpr int Ln = 256;
constexpr int Wn = 192;
constexpr int NC = Tn / Ln;          // 1024
constexpr size_t OFF_MF   = 0;
constexpr size_t OFF_MB   = (size_t)Tn;
constexpr size_t OFF_MATF = 2*(size_t)Tn;
constexpr size_t OFF_MATB = OFF_MATF + 4*(size_t)NC;
constexpr size_t OFF_SF   = OFF_MATB + 4*(size_t)NC;
constexpr size_t OFF_SB   = OFF_SF + NC;
constexpr size_t OFF_P    = OFF_SB + NC;
constexpr size_t OFF_W    = OFF_P + Kn*Kn;
constexpr size_t OFF_CK   = OFF_W + Kn;
constexpr size_t OFF_MV   = OFF_CK + Kn;
constexpr size_t OFF_IV   = OFF_MV + Kn*Fn;

__global__ __launch_bounds__(64) void prep1_kernel(
    const float* beta_logits, const float* pi_logits,
    const float* means, const float* log_vars, float* ws)
{
  int k = threadIdx.x;
  if (k < Kn) {
    float row[Kn];
    float mx = -1e30f;
#pragma unroll
    for (int j = 0; j < Kn; ++j) { row[j] = pi_logits[k*Kn + j]; mx = fmaxf(mx, row[j]); }
    float s = 0.f;
#pragma unroll
    for (int j = 0; j < Kn; ++j) { row[j] = expf(row[j] - mx); s += row[j]; }
    float invs = 1.0f / s;
#pragma unroll
    for (int j = 0; j < Kn; ++j) ws[OFF_P + k*Kn + j] = row[j] * invs;
    float ck = 0.f;
#pragma unroll
    for (int f = 0; f < Fn; ++f) {
      float lv  = log_vars[k*Fn + f];
      float var = expf(lv) + 1e-6f;
      float iv  = 1.0f / var;
      float mu  = means[k*Fn + f];
      ws[OFF_MV + k*Fn + f] = mu * iv;
      ws[OFF_IV + k*Fn + f] = iv;
      ck += mu*mu*iv + logf(6.2831853071795864f * var);
    }
    ws[OFF_CK + k] = ck;
  } else if (k == Kn) {
    float cp = 1.f;
#pragma unroll
    for (int i = 0; i < Kn; ++i) {
      float b = 1.0f / (1.0f + expf(-beta_logits[i]));
      ws[OFF_W + i] = b * cp;
      cp *= (1.0f - b);
    }
  }
}

__global__ __launch_bounds__(64) void scan1_kernel(
    const float* __restrict__ obs, float* ws, float* out)
{
  __shared__ float xsh[2][32];
  const int tid = threadIdx.x;
  const int g   = tid >> 5;
  const int jj  = tid & 31;
  const bool act = (jj < Kn);
  const bool isF = (blockIdx.x < (NC/2));
  const int c = isF ? ((int)blockIdx.x*2 + g) : (((int)blockIdx.x - NC/2)*2 + g);

  float Pv[Kn];
  float mv[Fn], iv[Fn];
  float ck = 0.f;
  if (act) {
#pragma unroll
    for (int k = 0; k < Kn; ++k)
      Pv[k] = isF ? ws[OFF_P + k*Kn + jj] : ws[OFF_P + jj*Kn + k];
#pragma unroll
    for (int f = 0; f < Fn; ++f) {
      mv[f] = ws[OFF_MV + jj*Fn + f];
      iv[f] = ws[OFF_IV + jj*Fn + f];
    }
    ck = ws[OFF_CK + jj];
  } else {
#pragma unroll
    for (int k = 0; k < Kn; ++k) Pv[k] = 0.f;
#pragma unroll
    for (int f = 0; f < Fn; ++f) { mv[f] = 0.f; iv[f] = 0.f; }
  }

  float Ma = 1.f, Mc = 0.f, Md = 1.f;
  float* mArr = ws + (isF ? OFF_MF : OFF_MB);
  float* uOut = out + (isF ? (size_t)0 : (size_t)Tn * Kn);

  auto emexp = [&](int t) -> float {
    const float4* o4 = (const float4*)(obs + (size_t)t * Fn);
    float4 A = o4[0], B = o4[1], C4 = o4[2], D = o4[3];
    float o[16] = {A.x,A.y,A.z,A.w, B.x,B.y,B.z,B.w,
                   C4.x,C4.y,C4.z,C4.w, D.x,D.y,D.z,D.w};
    float s1a=0.f, s1b=0.f, s2a=0.f, s2b=0.f;
#pragma unroll
    for (int f = 0; f < Fn; f += 2) {
      s1a = fmaf(o[f]*o[f],     iv[f],   s1a);
      s1b = fmaf(o[f+1]*o[f+1], iv[f+1], s1b);
      s2a = fmaf(o[f],   mv[f],   s2a);
      s2b = fmaf(o[f+1], mv[f+1], s2b);
    }
    float em = -0.5f * ((s1a + s1b) - 2.0f*(s2a + s2b) + ck);
    return __expf(em);
  };
  auto mobius = [&](float m) {
    float na = m * Ma;
    float nc = fmaf(EPSF, Mc, na);
    float nd = EPSF * Md;
    float mx = fmaxf(nc, nd);
    float lam = (mx > 0.f) ? (1.0f/mx) : 1.0f;
    Ma = na*lam; Mc = nc*lam; Md = nd*lam;
  };
  auto matvec = [&]() -> float {
    float a0=0.f, a1=0.f, a2=0.f, a3=0.f;
#pragma unroll
    for (int k = 0; k < Kn; k += 4) {
      a0 = fmaf(xsh[g][k+0], Pv[k+0], a0);
      a1 = fmaf(xsh[g][k+1], Pv[k+1], a1);
      a2 = fmaf(xsh[g][k+2], Pv[k+2], a2);
      a3 = fmaf(xsh[g][k+3], Pv[k+3], a3);
    }
    return (a0+a1) + (a2+a3);
  };

  if (isF) {
    const int bodyStart = c * Ln;
    const int tend = bodyStart + Ln - 1;
    const int t0 = (c == 0) ? 0 : (bodyStart - Wn);
    float wj = act ? ws[OFF_W + jj] : 0.f;
    float u, im, m;
    {
      float e = emexp(t0);
      u = (c == 0) ? (wj * e) : (act ? 0.05f * e : 0.f);
    }
    m = groupReduce32(u);
    if (t0 >= bodyStart) {
      if (jj == 0) mArr[t0] = m;
      mobius(m);
      if (act) uOut[(size_t)t0 * Kn + jj] = u;
    }
    if (m < 1e-35f) { u = act ? 0.05f : 0.f; im = 1.0f; } else im = 1.0f / m;

    for (int t = t0 + 1; t <= tend; ++t) {
      xsh[g][jj] = u;
      float acc = matvec();
      float e = emexp(t);
      u = acc * (e * im);
      m = groupReduce32(u);
      if (t >= bodyStart) {
        if (jj == 0) mArr[t] = m;
        mobius(m);
        if (act) uOut[(size_t)t * Kn + jj] = u;
      }
      if (m < 1e-35f) { u = act ? 0.05f : 0.f; im = 1.0f; } else im = 1.0f / m;
    }
    if (jj == 0) {
      float4* M4 = (float4*)(ws + OFF_MATF);
      M4[c] = make_float4(Ma, Mc, Md, 0.f);
    }
  } else {
    const int bodyStart = c * Ln;
    const int top = bodyStart + Ln - 1;
    int r0 = top + Wn; if (r0 > Tn - 1) r0 = Tn - 1;
    float u = act ? 0.05f : 0.f;
    float im = 1.0f, m;
    for (int r = r0 - 1; r >= bodyStart; --r) {
      const int src = r + 1;
      float e = emexp(src);
      xsh[g][jj] = u * e;
      float acc = matvec();
      u = acc * im;
      m = groupReduce32(u);
      if (r <= top) {
        if (jj == 0) mArr[src] = m;
        mobius(m);
        if (act) uOut[(size_t)r * Kn + jj] = u;
      }
      if (m < 1e-35f) { u = act ? 0.05f : 0.f; im = 1.0f; } else im = 1.0f / m;
    }
    if (jj == 0) {
      float4* M4 = (float4*)(ws + OFF_MATB);
      M4[NC - 1 - c] = make_float4(Ma, Mc, Md, 0.f);
    }
  }
}

__global__ __launch_bounds__(128) void combine1_kernel(float* ws)
{
  const int wid  = threadIdx.x >> 6;
  const int lane = threadIdx.x & 63;
  const float4* M4 = (const float4*)(ws + (wid == 0 ? OFF_MATF : OFF_MATB));
  float* sArr = ws + (wid == 0 ? OFF_SF : OFF_SB);
  const float s0 = (wid == 0) ? 1.0f : 20.0f;
  constexpr int PG = NC / 64;

  float a = 1.f, cc = 0.f, d = 1.f;
  for (int i = 0; i < PG; ++i) {
    float4 mm = M4[lane*PG + i];
    float na = mm.x * a;
    float nc = fmaf(mm.y, a, mm.z * cc);
    float nd = mm.z * d;
    float mx = fmaxf(na, fmaxf(nc, nd));
    float lam = (mx > 0.f) ? (1.0f/mx) : 1.0f;
    a = na*lam; cc = nc*lam; d = nd*lam;
  }
  float ia = a, ic = cc, id = d;
  for (int off = 1; off < 64; off <<= 1) {
    float pa = __shfl_up(ia, off, 64);
    float pc = __shfl_up(ic, off, 64);
    float pd = __shfl_up(id, off, 64);
    if (lane >= off) {
      float na = ia * pa;
      float nc = fmaf(ic, pa, id * pc);
      float nd = id * pd;
      float mx = fmaxf(na, fmaxf(nc, nd));
      float lam = (mx > 0.f) ? (1.0f/mx) : 1.0f;
      ia = na*lam; ic = nc*lam; id = nd*lam;
    }
  }
  float ea = __shfl_up(ia, 1, 64);
  float ec = __shfl_up(ic, 1, 64);
  float ed = __shfl_up(id, 1, 64);
  if (lane == 0) { ea = 1.f; ec = 0.f; ed = 1.f; }
  float s;
  { float num = ea * s0; float den = fmaf(ec, s0, ed);
    s = (den > 0.f) ? num/den : 0.f; }
  for (int i = 0; i < PG; ++i) {
    sArr[lane*PG + i] = s;
    float4 mm = M4[lane*PG + i];
    float num = mm.x * s; float den = fmaf(mm.y, s, mm.z);
    s = (den > 0.f) ? num/den : 0.f;
  }
}

__global__ __launch_bounds__(64) void scale1_kernel(float* ws, float* out)
{
  const int tid = threadIdx.x;
  const int g   = tid >> 5;
  const int jj  = tid & 31;
  const bool act = (jj < Kn);
  const bool isF = (blockIdx.x < (NC/2));
  const int c = isF ? ((int)blockIdx.x*2 + g) : (((int)blockIdx.x - NC/2)*2 + g);

  if (isF) {
    const float* mArr = ws + OFF_MF;
    float* A = out;
    float s = ws[OFF_SF + c];
    const int t0 = c * Ln;
    for (int t = t0; t < t0 + Ln; ++t) {
      float mm = mArr[t];
      float z = s * mm;
      float den = z + EPSF;
      float inv = 1.0f / den;
      float scale = s * inv;
      float val = 0.f;
      if (act) {
        size_t idx = (size_t)t * Kn + jj;
        val = A[idx] * scale;
        A[idx] = val;
      }
      s = z * inv;
      if (t == Tn - 1) {
        float tot = groupReduce32(val);
        if (jj == 0) out[(size_t)2 * Tn * Kn] = logf(tot + EPSF);
      }
    }
  } else {
    const float* mArr = ws + OFF_MB;
    float* B = out + (size_t)Tn * Kn;
    const int slot = NC - 1 - c;
    float s = ws[OFF_SB + slot];
    const int bodyStart = c * Ln;
    const int top = bodyStart + Ln - 1;
    for (int r = top; r >= bodyStart; --r) {
      if (r == Tn - 1) {
        if (act) B[(size_t)r * Kn + jj] = 1.0f;
        continue;
      }
      float mm = mArr[r + 1];
      float z = s * mm;
      float den = z + EPSF;
      float inv = 1.0f / den;
      float scale = s * inv;
      if (act) {
        size_t idx = (size_t)r * Kn + jj;
        B[idx] = B[idx] * scale;
      }
      s = z * inv;
    }
  }
}
} // namespace v1

extern "C" void kernel_launch(void* const* d_in, const int* in_sizes, int n_in,
                              void* d_out, int out_size, void* d_ws, size_t ws_size,
                              hipStream_t stream) {
  const float* obs         = (const float*)d_in[0];
  const float* beta_logits = (const float*)d_in[1];
  const float* pi_logits   = (const float*)d_in[2];
  const float* means       = (const float*)d_in[3];
  const float* log_vars    = (const float*)d_in[4];
  float* out = (float*)d_out;
  float* ws  = (float*)d_ws;

  const size_t need = OFF_END * sizeof(float);   // ~25.3 MB
  if (ws_size >= need) {
    hipLaunchKernelGGL(prep_kernel, dim3(1), dim3(64), 0, stream,
                       beta_logits, pi_logits, means, log_vars, ws);
    hipLaunchKernelGGL(emis_kernel, dim3((Tn*Kn + 255)/256), dim3(256), 0, stream, obs, ws);
    hipLaunchKernelGGL(scan2_kernel, dim3(NC2), dim3(64), 0, stream, ws, out);
    hipLaunchKernelGGL(combine2_kernel, dim3(1), dim3(128), 0, stream, ws, out);
    hipLaunchKernelGGL(scale2_kernel, dim3(NC2), dim3(64), 0, stream, ws, out);
  } else {
    hipLaunchKernelGGL(v1::prep1_kernel, dim3(1), dim3(64), 0, stream,
                       beta_logits, pi_logits, means, log_vars, ws);
    hipLaunchKernelGGL(v1::scan1_kernel, dim3(v1::NC), dim3(64), 0, stream, obs, ws, out);
    hipLaunchKernelGGL(v1::combine1_kernel, dim3(1), dim3(128), 0, stream, ws);
    hipLaunchKernelGGL(v1::scale1_kernel, dim3(v1::NC), dim3(64), 0, stream, ws, out);
  }
}

// Round 3
// 234.485 us; speedup vs baseline: 1.8610x; 1.2932x over previous
//
#include <hip/hip_runtime.h>

// HDP-HMM forward-backward, exact-semantics parallel decomposition. R3:
//  - DPP butterfly reduce (xor1/xor2 quad_perm, half_mirror, mirror + ds_swizzle xor16)
//    replaces 5-deep ds_swizzle shuffle chain (~650 -> ~170 cyc, hidden under matvec)
//  - Ln=64/Wn=96 -> 160 steps/chunk, 4096 chunks/dir, 128-thr blocks (4 groups),
//    16 waves/CU = 4/SIMD for latency hiding
//  - E prefetch depth 3; scale kernel same 4-group layout + rcp
//  - float4-vectorized emission kernel

namespace {
constexpr int Tn = 262144;
constexpr int Kn = 20;
constexpr int Fn = 16;
constexpr float EPSF = 1e-10f;
constexpr float TINY = 1e-35f;

constexpr int Ln2 = 64;
constexpr int Wn2 = 96;
constexpr int NC2 = Tn / Ln2;          // 4096 chunks per direction
constexpr int NBS = NC2 / 4;           // 1024 blocks per direction (4 chunks/block)

// ws layout (floats); total ~6.34M floats = 25.3 MB
constexpr size_t OFF_P    = 0;                   // P row-major [400]
constexpr size_t OFF_W    = 400;                 // stick weights [20]
constexpr size_t OFF_CK   = 420;                 // emission const [20]
constexpr size_t OFF_MVIV = 440;                 // float2 (mean*iv, iv) [640]
constexpr size_t OFF_E    = 1152;                // E[t*20+k] [Tn*20 + 64 pad]
constexpr size_t OFF_MSF  = OFF_E + (size_t)Tn*20 + 64;   // float2[Tn] fwd (m, 1/sigma)
constexpr size_t OFF_MSB  = OFF_MSF + 2*(size_t)Tn;       // float2[Tn] bwd
constexpr size_t OFF_MATF = OFF_MSB + 2*(size_t)Tn;       // [NC2][4]
constexpr size_t OFF_MATB = OFF_MATF + 4*(size_t)NC2;
constexpr size_t OFF_SF   = OFF_MATB + 4*(size_t)NC2;     // [NC2]
constexpr size_t OFF_SB   = OFF_SF + NC2;                 // [NC2]
constexpr size_t OFF_END  = OFF_SB + NC2;
}

#if __has_builtin(__builtin_amdgcn_rcpf)
#define FRCP(x) __builtin_amdgcn_rcpf(x)
#else
#define FRCP(x) (1.0f/(x))
#endif

template<int CTRL>
__device__ __forceinline__ float dpp_add(float v) {
  int s = __builtin_amdgcn_update_dpp(0, __float_as_int(v), CTRL, 0xF, 0xF, true);
  return v + __int_as_float(s);
}

// Sum across each 32-lane half, result broadcast to all lanes of the half.
// Butterfly: xor1 (quad_perm 1,0,3,2 = 0xB1), xor2 (quad_perm 2,3,0,1 = 0x4E),
// xor4-equiv (row_half_mirror 0x141, valid once quads uniform),
// xor8-equiv (row_mirror 0x140), then ds_swizzle xor16 (0x401F).
__device__ __forceinline__ float reduce32b(float v) {
  v = dpp_add<0xB1>(v);
  v = dpp_add<0x4E>(v);
  v = dpp_add<0x141>(v);
  v = dpp_add<0x140>(v);
  int x = __builtin_amdgcn_ds_swizzle(__float_as_int(v), 0x401F);
  return v + __int_as_float(x);
}

// ============================ prep ============================
__global__ __launch_bounds__(64) void prep_kernel(
    const float* beta_logits, const float* pi_logits,
    const float* means, const float* log_vars, float* ws)
{
  int k = threadIdx.x;
  if (k < Kn) {
    float row[Kn];
    float mx = -1e30f;
#pragma unroll
    for (int j = 0; j < Kn; ++j) { row[j] = pi_logits[k*Kn + j]; mx = fmaxf(mx, row[j]); }
    float s = 0.f;
#pragma unroll
    for (int j = 0; j < Kn; ++j) { row[j] = expf(row[j] - mx); s += row[j]; }
    float invs = 1.0f / s;
#pragma unroll
    for (int j = 0; j < Kn; ++j) ws[OFF_P + k*Kn + j] = row[j] * invs;
    float ck = 0.f;
#pragma unroll
    for (int f = 0; f < Fn; ++f) {
      float lv  = log_vars[k*Fn + f];
      float var = expf(lv) + 1e-6f;
      float iv  = 1.0f / var;
      float mu  = means[k*Fn + f];
      ((float2*)(ws + OFF_MVIV))[k*Fn + f] = make_float2(mu * iv, iv);
      ck += mu*mu*iv + logf(6.2831853071795864f * var);
    }
    ws[OFF_CK + k] = ck;
  } else if (k == Kn) {
    float cp = 1.f;
#pragma unroll
    for (int i = 0; i < Kn; ++i) {
      float b = 1.0f / (1.0f + expf(-beta_logits[i]));
      ws[OFF_W + i] = b * cp;
      cp *= (1.0f - b);
    }
  }
}

// ============================ emission ============================
// One thread computes 4 consecutive k for one t; float4 store.
__global__ __launch_bounds__(256) void emis_kernel(const float* __restrict__ obs, float* ws)
{
  int gid = blockIdx.x * 256 + threadIdx.x;
  if (gid >= Tn * 5) return;
  int t  = (int)((unsigned)gid / 5u);
  int k0 = (gid - t*5) * 4;
  const float4* o4 = (const float4*)(obs + (size_t)t * Fn);
  float4 Aq = o4[0], Bq = o4[1], Cq = o4[2], Dq = o4[3];
  float o[16] = {Aq.x,Aq.y,Aq.z,Aq.w, Bq.x,Bq.y,Bq.z,Bq.w,
                 Cq.x,Cq.y,Cq.z,Cq.w, Dq.x,Dq.y,Dq.z,Dq.w};
  float rr[4];
#pragma unroll
  for (int q = 0; q < 4; ++q) {
    int k = k0 + q;
    const float2* mviv = (const float2*)(ws + OFF_MVIV) + k*Fn;
    float ck = ws[OFF_CK + k];
    float s1 = 0.f, s2 = 0.f;
#pragma unroll
    for (int f = 0; f < Fn; ++f) {
      float2 c2 = mviv[f];
      s1 = fmaf(c2.y * o[f], o[f], s1);
      s2 = fmaf(c2.x, o[f], s2);
    }
    rr[q] = __expf(fmaf(-0.5f, s1 + ck, s2));
  }
  *(float4*)(ws + OFF_E + (size_t)t*20 + k0) = make_float4(rr[0], rr[1], rr[2], rr[3]);
}

// ============================ scan ============================
__global__ __launch_bounds__(128) void scan2_kernel(float* ws, float* out)
{
  __shared__ float4 xsh4[4][8];
  const int tid = threadIdx.x;
  const int g   = tid >> 5;
  const int jj  = tid & 31;
  const bool act = (jj < Kn);
  const float vReset = act ? 0.05f : 0.f;
  const bool isF = ((int)blockIdx.x < NBS);
  const int c = (isF ? (int)blockIdx.x : (int)blockIdx.x - NBS) * 4 + g;
  const float* E = ws + OFF_E;
  float* xg = (float*)&xsh4[g][0];

  float Pv[Kn];
#pragma unroll
  for (int k = 0; k < Kn; ++k)
    Pv[k] = act ? (isF ? ws[OFF_P + k*Kn + jj] : ws[OFF_P + jj*Kn + k]) : 0.f;

  float Ma = 1.f, Mc = 0.f, Md = 1.f;
  float2* msig = (float2*)(ws + (isF ? OFF_MSF : OFF_MSB));
  float* uOut = out + (isF ? (size_t)0 : (size_t)Tn * Kn);

  auto mobius = [&](float m) {
    float na = m * Ma;
    float nc = fmaf(EPSF, Mc, na);
    float nd = EPSF * Md;
    float mx = fmaxf(nc, nd);
    float lam = (mx > 0.f) ? FRCP(mx) : 1.0f;
    Ma = na*lam; Mc = nc*lam; Md = nd*lam;
  };
  auto matvec = [&]() -> float {
    float4 x0 = xsh4[g][0], x1 = xsh4[g][1], x2 = xsh4[g][2],
           x3 = xsh4[g][3], x4 = xsh4[g][4];
    float a0 = x0.x*Pv[0], a1 = x0.y*Pv[1], a2 = x0.z*Pv[2], a3 = x0.w*Pv[3];
    a0 = fmaf(x1.x, Pv[4], a0); a1 = fmaf(x1.y, Pv[5], a1);
    a2 = fmaf(x1.z, Pv[6], a2); a3 = fmaf(x1.w, Pv[7], a3);
    a0 = fmaf(x2.x, Pv[8], a0); a1 = fmaf(x2.y, Pv[9], a1);
    a2 = fmaf(x2.z, Pv[10], a2); a3 = fmaf(x2.w, Pv[11], a3);
    a0 = fmaf(x3.x, Pv[12], a0); a1 = fmaf(x3.y, Pv[13], a1);
    a2 = fmaf(x3.z, Pv[14], a2); a3 = fmaf(x3.w, Pv[15], a3);
    a0 = fmaf(x4.x, Pv[16], a0); a1 = fmaf(x4.y, Pv[17], a1);
    a2 = fmaf(x4.z, Pv[18], a2); a3 = fmaf(x4.w, Pv[19], a3);
    return (a0+a1) + (a2+a3);
  };

  if (isF) {
    const int bodyStart = c * Ln2;
    const int tend = bodyStart + Ln2 - 1;
    const int t0 = (c == 0) ? 0 : (bodyStart - Wn2);
    float wj = act ? ws[OFF_W + jj] : 0.f;
    float e0 = E[t0*20 + jj];
    float v = act ? ((c == 0) ? wj * e0 : 0.05f * e0) : 0.f;
    float sv = reduce32b(v);
    float m = sv;                               // A_prev = 1
    float iV = (sv > TINY) ? FRCP(sv) : 1.0f;
    if (sv <= TINY) v = vReset;
    if (c == 0) {
      if (jj == 0) msig[0] = make_float2(m, iV);
      mobius(m);
      if (act) uOut[jj] = v;
    }
    float A = m * iV;
    float rho = (m > TINY) ? FRCP(m) : 1.0f;
    float e1 = E[(t0+1)*20 + jj];
    float e2 = E[(t0+2)*20 + jj];
    float e3 = E[(t0+3)*20 + jj];

#define FWD_STEP(REC)                                                     \
    {                                                                     \
      xg[jj] = v;                                                         \
      float acc = matvec();                                               \
      float er = e1 * rho;                                                \
      e1 = e2; e2 = e3; e3 = E[(t+3)*20 + jj];                            \
      v = acc * er;                                                       \
      float sv2 = reduce32b(v);                                           \
      float mn = sv2 * A;                                                 \
      float iVn = (sv2 > TINY) ? FRCP(sv2) : 1.0f;                        \
      if (sv2 <= TINY) v = vReset;                                        \
      if (REC) {                                                          \
        if (jj == 0) msig[t] = make_float2(mn, iVn);                      \
        mobius(mn);                                                       \
        if (act) uOut[(size_t)t*Kn + jj] = v;                             \
      }                                                                   \
      A = mn * iVn;                                                       \
      rho = (mn > TINY) ? FRCP(mn) : 1.0f;                                \
    }

    for (int t = t0 + 1; t < bodyStart; ++t) FWD_STEP(false)
    const int bstart2 = (c == 0) ? 1 : bodyStart;
    for (int t = bstart2; t <= tend; ++t) FWD_STEP(true)
#undef FWD_STEP
    if (jj == 0) ((float4*)(ws + OFF_MATF))[c] = make_float4(Ma, Mc, Md, 0.f);
  } else {
    const int bodyStart = c * Ln2;
    const int top = bodyStart + Ln2 - 1;
    int r0 = top + Wn2; if (r0 > Tn - 1) r0 = Tn - 1;   // r0==Tn-1 => exact init
    float v = vReset;                                   // uniform direction
    float sv = reduce32b(v);                            // ~1.0
    float iV = (sv > TINY) ? FRCP(sv) : 1.0f;
    float A = iV;                                       // m_prev = 1 convention
    float rho = 1.0f;
    float e1 = E[r0*20 + jj];
    float e2 = E[(r0-1)*20 + jj];
    float e3 = E[(r0-2)*20 + jj];

#define BWD_STEP(REC)                                                     \
    {                                                                     \
      xg[jj] = v * e1;                                                    \
      float acc = matvec();                                               \
      v = acc * rho;                                                      \
      e1 = e2; e2 = e3; e3 = E[(r-2)*20 + jj];                            \
      float sv2 = reduce32b(v);                                           \
      float mn = sv2 * A;                                                 \
      float iVn = (sv2 > TINY) ? FRCP(sv2) : 1.0f;                        \
      if (sv2 <= TINY) v = vReset;                                        \
      if (REC) {                                                          \
        if (jj == 0) msig[r+1] = make_float2(mn, iVn);                    \
        mobius(mn);                                                       \
        if (act) uOut[(size_t)r*Kn + jj] = v;                             \
      }                                                                   \
      A = mn * iVn;                                                       \
      rho = (mn > TINY) ? FRCP(mn) : 1.0f;                                \
    }

    for (int r = r0 - 1; r > top; --r) BWD_STEP(false)
    int rb = (r0 - 1 < top) ? (r0 - 1) : top;
    for (int r = rb; r >= bodyStart; --r) BWD_STEP(true)
#undef BWD_STEP
    if (jj == 0) ((float4*)(ws + OFF_MATB))[NC2 - 1 - c] = make_float4(Ma, Mc, Md, 0.f);
  }
}

// ============================ combine ============================
// wave0: forward (s0=1); wave1: backward (s0=20, slots in application order).
__global__ __launch_bounds__(128) void combine2_kernel(float* ws, float* out)
{
  const int wid  = threadIdx.x >> 6;
  const int lane = threadIdx.x & 63;
  const float4* M4 = (const float4*)(ws + (wid == 0 ? OFF_MATF : OFF_MATB));
  float* sArr = ws + (wid == 0 ? OFF_SF : OFF_SB);
  const float s0 = (wid == 0) ? 1.0f : 20.0f;
  constexpr int PG = NC2 / 64;   // 64

  float a = 1.f, cc = 0.f, d = 1.f;
  for (int i = 0; i < PG; ++i) {
    float4 mm = M4[lane*PG + i];
    float na = mm.x * a;
    float nc = fmaf(mm.y, a, mm.z * cc);
    float nd = mm.z * d;
    float mx = fmaxf(na, fmaxf(nc, nd));
    float lam = (mx > 0.f) ? (1.0f/mx) : 1.0f;
    a = na*lam; cc = nc*lam; d = nd*lam;
  }
  float ia = a, ic = cc, id = d;
  for (int off = 1; off < 64; off <<= 1) {
    float pa = __shfl_up(ia, off, 64);
    float pc = __shfl_up(ic, off, 64);
    float pd = __shfl_up(id, off, 64);
    if (lane >= off) {
      float na = ia * pa;
      float nc = fmaf(ic, pa, id * pc);
      float nd = id * pd;
      float mx = fmaxf(na, fmaxf(nc, nd));
      float lam = (mx > 0.f) ? (1.0f/mx) : 1.0f;
      ia = na*lam; ic = nc*lam; id = nd*lam;
    }
  }
  if (wid == 0 && lane == 63) {
    float den = fmaf(ic, s0, id);
    float sfin = (den > 0.f) ? (ia * s0)/den : 0.f;
    out[(size_t)2 * Tn * Kn] = logf(sfin + EPSF);
  }
  float ea = __shfl_up(ia, 1, 64);
  float ec = __shfl_up(ic, 1, 64);
  float ed = __shfl_up(id, 1, 64);
  if (lane == 0) { ea = 1.f; ec = 0.f; ed = 1.f; }
  float s;
  { float num = ea * s0; float den = fmaf(ec, s0, ed);
    s = (den > 0.f) ? num/den : 0.f; }
  for (int i = 0; i < PG; ++i) {
    sArr[lane*PG + i] = s;
    float4 mm = M4[lane*PG + i];
    float num = mm.x * s; float den = fmaf(mm.y, s, mm.z);
    s = (den > 0.f) ? num/den : 0.f;
  }
}

// ============================ scale ============================
__global__ __launch_bounds__(128) void scale2_kernel(float* ws, float* out)
{
  const int tid = threadIdx.x;
  const int g   = tid >> 5;
  const int jj  = tid & 31;
  const bool act = (jj < Kn);
  const bool isF = ((int)blockIdx.x < NBS);
  const int c = (isF ? (int)blockIdx.x : (int)blockIdx.x - NBS) * 4 + g;

  if (isF) {
    const float2* msig = (const float2*)(ws + OFF_MSF);
    float* A = out;
    float s = ws[OFF_SF + c];
    const int t0 = c * Ln2;
#pragma unroll 4
    for (int t = t0; t < t0 + Ln2; ++t) {
      float2 p = msig[t];
      float z = s * p.x;
      float den = z + EPSF;
      float sn = z * FRCP(den);
      if (act) {
        size_t idx = (size_t)t * Kn + jj;
        A[idx] = A[idx] * (sn * p.y);
      }
      s = sn;
    }
  } else {
    const float2* msig = (const float2*)(ws + OFF_MSB);
    float* B = out + (size_t)Tn * Kn;
    const int slot = NC2 - 1 - c;
    float s = ws[OFF_SB + slot];
    const int bodyStart = c * Ln2;
    const int top = bodyStart + Ln2 - 1;
#pragma unroll 4
    for (int r = top; r >= bodyStart; --r) {
      if (r == Tn - 1) {
        if (act) B[(size_t)r * Kn + jj] = 1.0f;
        continue;
      }
      float2 p = msig[r + 1];
      float z = s * p.x;
      float den = z + EPSF;
      float sn = z * FRCP(den);
      if (act) {
        size_t idx = (size_t)r * Kn + jj;
        B[idx] = B[idx] * (sn * p.y);
      }
      s = sn;
    }
  }
}

extern "C" void kernel_launch(void* const* d_in, const int* in_sizes, int n_in,
                              void* d_out, int out_size, void* d_ws, size_t ws_size,
                              hipStream_t stream) {
  const float* obs         = (const float*)d_in[0];
  const float* beta_logits = (const float*)d_in[1];
  const float* pi_logits   = (const float*)d_in[2];
  const float* means       = (const float*)d_in[3];
  const float* log_vars    = (const float*)d_in[4];
  float* out = (float*)d_out;
  float* ws  = (float*)d_ws;   // needs ~25.3 MB (confirmed available in R2)

  hipLaunchKernelGGL(prep_kernel, dim3(1), dim3(64), 0, stream,
                     beta_logits, pi_logits, means, log_vars, ws);
  hipLaunchKernelGGL(emis_kernel, dim3((Tn*5 + 255)/256), dim3(256), 0, stream, obs, ws);
  hipLaunchKernelGGL(scan2_kernel, dim3(2*NBS), dim3(128), 0, stream, ws, out);
  hipLaunchKernelGGL(combine2_kernel, dim3(1), dim3(128), 0, stream, ws, out);
  hipLaunchKernelGGL(scale2_kernel, dim3(2*NBS), dim3(128), 0, stream, ws, out);
}

// Round 4
// 200.965 us; speedup vs baseline: 2.1714x; 1.1668x over previous
//
#include <hip/hip_runtime.h>

// HDP-HMM forward-backward, exact-semantics parallel decomposition. R4:
//  - Wn 96->48 (measured contraction tau~0.63/step => err ~3e-10, threshold 0.46)
//  - scale kernel split: serial sigma chain into LDS, then fully-coalesced float4 RMW
//  - combine loops unrolled for load pipelining

namespace {
constexpr int Tn = 262144;
constexpr int Kn = 20;
constexpr int Fn = 16;
constexpr float EPSF = 1e-10f;
constexpr float TINY = 1e-35f;

constexpr int Ln2 = 64;
constexpr int Wn2 = 48;
constexpr int NC2 = Tn / Ln2;          // 4096 chunks per direction
constexpr int NBS = NC2 / 4;           // 1024 blocks per direction (4 chunks/block)

// ws layout (floats); ~25.3 MB
constexpr size_t OFF_P    = 0;                   // P row-major [400]
constexpr size_t OFF_W    = 400;                 // stick weights [20]
constexpr size_t OFF_CK   = 420;                 // emission const [20]
constexpr size_t OFF_MVIV = 440;                 // float2 (mean*iv, iv) [640]
constexpr size_t OFF_E    = 1152;                // E[t*20+k] [Tn*20 + 64 pad]
constexpr size_t OFF_MSF  = OFF_E + (size_t)Tn*20 + 64;   // float2[Tn] fwd (m, 1/sigma)
constexpr size_t OFF_MSB  = OFF_MSF + 2*(size_t)Tn;       // float2[Tn] bwd
constexpr size_t OFF_MATF = OFF_MSB + 2*(size_t)Tn;       // [NC2][4]
constexpr size_t OFF_MATB = OFF_MATF + 4*(size_t)NC2;
constexpr size_t OFF_SF   = OFF_MATB + 4*(size_t)NC2;     // [NC2]
constexpr size_t OFF_SB   = OFF_SF + NC2;                 // [NC2]
constexpr size_t OFF_END  = OFF_SB + NC2;
}

#if __has_builtin(__builtin_amdgcn_rcpf)
#define FRCP(x) __builtin_amdgcn_rcpf(x)
#else
#define FRCP(x) (1.0f/(x))
#endif

template<int CTRL>
__device__ __forceinline__ float dpp_add(float v) {
  int s = __builtin_amdgcn_update_dpp(0, __float_as_int(v), CTRL, 0xF, 0xF, true);
  return v + __int_as_float(s);
}

// Sum across each 32-lane half, broadcast to all lanes of the half.
__device__ __forceinline__ float reduce32b(float v) {
  v = dpp_add<0xB1>(v);     // xor1 (quad_perm 1,0,3,2)
  v = dpp_add<0x4E>(v);     // xor2 (quad_perm 2,3,0,1)
  v = dpp_add<0x141>(v);    // row_half_mirror == xor4 once quads uniform
  v = dpp_add<0x140>(v);    // row_mirror == xor8 once octs uniform
  int x = __builtin_amdgcn_ds_swizzle(__float_as_int(v), 0x401F);  // xor16
  return v + __int_as_float(x);
}

// ============================ prep ============================
__global__ __launch_bounds__(64) void prep_kernel(
    const float* beta_logits, const float* pi_logits,
    const float* means, const float* log_vars, float* ws)
{
  int k = threadIdx.x;
  if (k < Kn) {
    float row[Kn];
    float mx = -1e30f;
#pragma unroll
    for (int j = 0; j < Kn; ++j) { row[j] = pi_logits[k*Kn + j]; mx = fmaxf(mx, row[j]); }
    float s = 0.f;
#pragma unroll
    for (int j = 0; j < Kn; ++j) { row[j] = expf(row[j] - mx); s += row[j]; }
    float invs = 1.0f / s;
#pragma unroll
    for (int j = 0; j < Kn; ++j) ws[OFF_P + k*Kn + j] = row[j] * invs;
    float ck = 0.f;
#pragma unroll
    for (int f = 0; f < Fn; ++f) {
      float lv  = log_vars[k*Fn + f];
      float var = expf(lv) + 1e-6f;
      float iv  = 1.0f / var;
      float mu  = means[k*Fn + f];
      ((float2*)(ws + OFF_MVIV))[k*Fn + f] = make_float2(mu * iv, iv);
      ck += mu*mu*iv + logf(6.2831853071795864f * var);
    }
    ws[OFF_CK + k] = ck;
  } else if (k == Kn) {
    float cp = 1.f;
#pragma unroll
    for (int i = 0; i < Kn; ++i) {
      float b = 1.0f / (1.0f + expf(-beta_logits[i]));
      ws[OFF_W + i] = b * cp;
      cp *= (1.0f - b);
    }
  }
}

// ============================ emission ============================
__global__ __launch_bounds__(256) void emis_kernel(const float* __restrict__ obs, float* ws)
{
  int gid = blockIdx.x * 256 + threadIdx.x;
  if (gid >= Tn * 5) return;
  int t  = (int)((unsigned)gid / 5u);
  int k0 = (gid - t*5) * 4;
  const float4* o4 = (const float4*)(obs + (size_t)t * Fn);
  float4 Aq = o4[0], Bq = o4[1], Cq = o4[2], Dq = o4[3];
  float o[16] = {Aq.x,Aq.y,Aq.z,Aq.w, Bq.x,Bq.y,Bq.z,Bq.w,
                 Cq.x,Cq.y,Cq.z,Cq.w, Dq.x,Dq.y,Dq.z,Dq.w};
  float rr[4];
#pragma unroll
  for (int q = 0; q < 4; ++q) {
    int k = k0 + q;
    const float2* mviv = (const float2*)(ws + OFF_MVIV) + k*Fn;
    float ck = ws[OFF_CK + k];
    float s1 = 0.f, s2 = 0.f;
#pragma unroll
    for (int f = 0; f < Fn; ++f) {
      float2 c2 = mviv[f];
      s1 = fmaf(c2.y * o[f], o[f], s1);
      s2 = fmaf(c2.x, o[f], s2);
    }
    rr[q] = __expf(fmaf(-0.5f, s1 + ck, s2));
  }
  *(float4*)(ws + OFF_E + (size_t)t*20 + k0) = make_float4(rr[0], rr[1], rr[2], rr[3]);
}

// ============================ scan ============================
__global__ __launch_bounds__(128) void scan2_kernel(float* ws, float* out)
{
  __shared__ float4 xsh4[4][8];
  const int tid = threadIdx.x;
  const int g   = tid >> 5;
  const int jj  = tid & 31;
  const bool act = (jj < Kn);
  const float vReset = act ? 0.05f : 0.f;
  const bool isF = ((int)blockIdx.x < NBS);
  const int c = (isF ? (int)blockIdx.x : (int)blockIdx.x - NBS) * 4 + g;
  const float* E = ws + OFF_E;
  float* xg = (float*)&xsh4[g][0];

  float Pv[Kn];
#pragma unroll
  for (int k = 0; k < Kn; ++k)
    Pv[k] = act ? (isF ? ws[OFF_P + k*Kn + jj] : ws[OFF_P + jj*Kn + k]) : 0.f;

  float Ma = 1.f, Mc = 0.f, Md = 1.f;
  float2* msig = (float2*)(ws + (isF ? OFF_MSF : OFF_MSB));
  float* uOut = out + (isF ? (size_t)0 : (size_t)Tn * Kn);

  auto mobius = [&](float m) {
    float na = m * Ma;
    float nc = fmaf(EPSF, Mc, na);
    float nd = EPSF * Md;
    float mx = fmaxf(nc, nd);
    float lam = (mx > 0.f) ? FRCP(mx) : 1.0f;
    Ma = na*lam; Mc = nc*lam; Md = nd*lam;
  };
  auto matvec = [&]() -> float {
    float4 x0 = xsh4[g][0], x1 = xsh4[g][1], x2 = xsh4[g][2],
           x3 = xsh4[g][3], x4 = xsh4[g][4];
    float a0 = x0.x*Pv[0], a1 = x0.y*Pv[1], a2 = x0.z*Pv[2], a3 = x0.w*Pv[3];
    a0 = fmaf(x1.x, Pv[4], a0); a1 = fmaf(x1.y, Pv[5], a1);
    a2 = fmaf(x1.z, Pv[6], a2); a3 = fmaf(x1.w, Pv[7], a3);
    a0 = fmaf(x2.x, Pv[8], a0); a1 = fmaf(x2.y, Pv[9], a1);
    a2 = fmaf(x2.z, Pv[10], a2); a3 = fmaf(x2.w, Pv[11], a3);
    a0 = fmaf(x3.x, Pv[12], a0); a1 = fmaf(x3.y, Pv[13], a1);
    a2 = fmaf(x3.z, Pv[14], a2); a3 = fmaf(x3.w, Pv[15], a3);
    a0 = fmaf(x4.x, Pv[16], a0); a1 = fmaf(x4.y, Pv[17], a1);
    a2 = fmaf(x4.z, Pv[18], a2); a3 = fmaf(x4.w, Pv[19], a3);
    return (a0+a1) + (a2+a3);
  };

  if (isF) {
    const int bodyStart = c * Ln2;
    const int tend = bodyStart + Ln2 - 1;
    const int t0 = (c == 0) ? 0 : (bodyStart - Wn2);
    float wj = act ? ws[OFF_W + jj] : 0.f;
    float e0 = E[t0*20 + jj];
    float v = act ? ((c == 0) ? wj * e0 : 0.05f * e0) : 0.f;
    float sv = reduce32b(v);
    float m = sv;                               // A_prev = 1
    float iV = (sv > TINY) ? FRCP(sv) : 1.0f;
    if (sv <= TINY) v = vReset;
    if (c == 0) {
      if (jj == 0) msig[0] = make_float2(m, iV);
      mobius(m);
      if (act) uOut[jj] = v;
    }
    float A = m * iV;
    float rho = (m > TINY) ? FRCP(m) : 1.0f;
    float e1 = E[(t0+1)*20 + jj];
    float e2 = E[(t0+2)*20 + jj];
    float e3 = E[(t0+3)*20 + jj];

#define FWD_STEP(REC)                                                     \
    {                                                                     \
      xg[jj] = v;                                                         \
      float acc = matvec();                                               \
      float er = e1 * rho;                                                \
      e1 = e2; e2 = e3; e3 = E[(t+3)*20 + jj];                            \
      v = acc * er;                                                       \
      float sv2 = reduce32b(v);                                           \
      float mn = sv2 * A;                                                 \
      float iVn = (sv2 > TINY) ? FRCP(sv2) : 1.0f;                        \
      if (sv2 <= TINY) v = vReset;                                        \
      if (REC) {                                                          \
        if (jj == 0) msig[t] = make_float2(mn, iVn);                      \
        mobius(mn);                                                       \
        if (act) uOut[(size_t)t*Kn + jj] = v;                             \
      }                                                                   \
      A = mn * iVn;                                                       \
      rho = (mn > TINY) ? FRCP(mn) : 1.0f;                                \
    }

    for (int t = t0 + 1; t < bodyStart; ++t) FWD_STEP(false)
    const int bstart2 = (c == 0) ? 1 : bodyStart;
    for (int t = bstart2; t <= tend; ++t) FWD_STEP(true)
#undef FWD_STEP
    if (jj == 0) ((float4*)(ws + OFF_MATF))[c] = make_float4(Ma, Mc, Md, 0.f);
  } else {
    const int bodyStart = c * Ln2;
    const int top = bodyStart + Ln2 - 1;
    int r0 = top + Wn2; if (r0 > Tn - 1) r0 = Tn - 1;   // r0==Tn-1 => exact init
    float v = vReset;                                   // uniform direction
    float sv = reduce32b(v);                            // ~1.0
    float iV = (sv > TINY) ? FRCP(sv) : 1.0f;
    float A = iV;                                       // m_prev = 1 convention
    float rho = 1.0f;
    float e1 = E[r0*20 + jj];
    float e2 = E[(r0-1)*20 + jj];
    float e3 = E[(r0-2)*20 + jj];

#define BWD_STEP(REC)                                                     \
    {                                                                     \
      xg[jj] = v * e1;                                                    \
      float acc = matvec();                                               \
      v = acc * rho;                                                      \
      e1 = e2; e2 = e3; e3 = E[(r-2)*20 + jj];                            \
      float sv2 = reduce32b(v);                                           \
      float mn = sv2 * A;                                                 \
      float iVn = (sv2 > TINY) ? FRCP(sv2) : 1.0f;                        \
      if (sv2 <= TINY) v = vReset;                                        \
      if (REC) {                                                          \
        if (jj == 0) msig[r+1] = make_float2(mn, iVn);                    \
        mobius(mn);                                                       \
        if (act) uOut[(size_t)r*Kn + jj] = v;                             \
      }                                                                   \
      A = mn * iVn;                                                       \
      rho = (mn > TINY) ? FRCP(mn) : 1.0f;                                \
    }

    for (int r = r0 - 1; r > top; --r) BWD_STEP(false)
    int rb = (r0 - 1 < top) ? (r0 - 1) : top;
    for (int r = rb; r >= bodyStart; --r) BWD_STEP(true)
#undef BWD_STEP
    if (jj == 0) ((float4*)(ws + OFF_MATB))[NC2 - 1 - c] = make_float4(Ma, Mc, Md, 0.f);
  }
}

// ============================ combine ============================
__global__ __launch_bounds__(128) void combine2_kernel(float* ws, float* out)
{
  const int wid  = threadIdx.x >> 6;
  const int lane = threadIdx.x & 63;
  const float4* M4 = (const float4*)(ws + (wid == 0 ? OFF_MATF : OFF_MATB));
  float* sArr = ws + (wid == 0 ? OFF_SF : OFF_SB);
  const float s0 = (wid == 0) ? 1.0f : 20.0f;
  constexpr int PG = NC2 / 64;   // 64

  float a = 1.f, cc = 0.f, d = 1.f;
#pragma unroll 4
  for (int i = 0; i < PG; ++i) {
    float4 mm = M4[lane*PG + i];
    float na = mm.x * a;
    float nc = fmaf(mm.y, a, mm.z * cc);
    float nd = mm.z * d;
    float mx = fmaxf(na, fmaxf(nc, nd));
    float lam = (mx > 0.f) ? (1.0f/mx) : 1.0f;
    a = na*lam; cc = nc*lam; d = nd*lam;
  }
  float ia = a, ic = cc, id = d;
  for (int off = 1; off < 64; off <<= 1) {
    float pa = __shfl_up(ia, off, 64);
    float pc = __shfl_up(ic, off, 64);
    float pd = __shfl_up(id, off, 64);
    if (lane >= off) {
      float na = ia * pa;
      float nc = fmaf(ic, pa, id * pc);
      float nd = id * pd;
      float mx = fmaxf(na, fmaxf(nc, nd));
      float lam = (mx > 0.f) ? (1.0f/mx) : 1.0f;
      ia = na*lam; ic = nc*lam; id = nd*lam;
    }
  }
  if (wid == 0 && lane == 63) {
    float den = fmaf(ic, s0, id);
    float sfin = (den > 0.f) ? (ia * s0)/den : 0.f;
    out[(size_t)2 * Tn * Kn] = logf(sfin + EPSF);
  }
  float ea = __shfl_up(ia, 1, 64);
  float ec = __shfl_up(ic, 1, 64);
  float ed = __shfl_up(id, 1, 64);
  if (lane == 0) { ea = 1.f; ec = 0.f; ed = 1.f; }
  float s;
  { float num = ea * s0; float den = fmaf(ec, s0, ed);
    s = (den > 0.f) ? num/den : 0.f; }
#pragma unroll 4
  for (int i = 0; i < PG; ++i) {
    sArr[lane*PG + i] = s;
    float4 mm = M4[lane*PG + i];
    float num = mm.x * s; float den = fmaf(mm.y, s, mm.z);
    s = (den > 0.f) ? num/den : 0.f;
  }
}

// ============================ scale ============================
// Phase 1: per chunk, serial sigma chain (all lanes redundant) into LDS.
// Phase 2: fully-coalesced float4 RMW (20 floats/row = exactly 5 quads).
__global__ __launch_bounds__(128) void scale2_kernel(float* ws, float* out)
{
  __shared__ float sig[4][Ln2];
  const int tid = threadIdx.x;
  const int g   = tid >> 5;
  const int jj  = tid & 31;
  const bool isF = ((int)blockIdx.x < NBS);
  const int c = (isF ? (int)blockIdx.x : (int)blockIdx.x - NBS) * 4 + g;
  constexpr int QPC = Ln2 * Kn / 4;   // float4 quads per chunk = 320

  if (isF) {
    const float2* msig = (const float2*)(ws + OFF_MSF);
    float s = ws[OFF_SF + c];
    const int t0 = c * Ln2;
    for (int i = 0; i < Ln2; ++i) {
      float2 p = msig[t0 + i];
      float z = s * p.x;
      float sn = z * FRCP(z + EPSF);
      if (jj == 0) sig[g][i] = sn * p.y;
      s = sn;
    }
    __syncthreads();
    float4* A4 = (float4*)out + (size_t)c * QPC;
#pragma unroll
    for (int i = jj; i < QPC; i += 32) {
      int tl = i / 5;
      float sg = sig[g][tl];
      float4 v = A4[i];
      v.x *= sg; v.y *= sg; v.z *= sg; v.w *= sg;
      A4[i] = v;
    }
  } else {
    const float2* msig = (const float2*)(ws + OFF_MSB);
    const int slot = NC2 - 1 - c;
    float s = ws[OFF_SB + slot];
    const int bodyStart = c * Ln2;
    const int top = bodyStart + Ln2 - 1;
    const bool lastChunk = (c == NC2 - 1);
    for (int r = top; r >= bodyStart; --r) {
      if (r == Tn - 1) {
        if (jj == 0) sig[g][Ln2 - 1] = 1.0f;   // placeholder, overridden below
        continue;
      }
      float2 p = msig[r + 1];
      float z = s * p.x;
      float sn = z * FRCP(z + EPSF);
      if (jj == 0) sig[g][r - bodyStart] = sn * p.y;
      s = sn;
    }
    __syncthreads();
    float4* B4 = (float4*)out + ((size_t)Tn * Kn) / 4 + (size_t)c * QPC;
#pragma unroll
    for (int i = jj; i < QPC; i += 32) {
      int tl = i / 5;
      if (lastChunk && tl == Ln2 - 1) {
        B4[i] = make_float4(1.f, 1.f, 1.f, 1.f);   // beta[T-1] = ones exactly
      } else {
        float sg = sig[g][tl];
        float4 v = B4[i];
        v.x *= sg; v.y *= sg; v.z *= sg; v.w *= sg;
        B4[i] = v;
      }
    }
  }
}

extern "C" void kernel_launch(void* const* d_in, const int* in_sizes, int n_in,
                              void* d_out, int out_size, void* d_ws, size_t ws_size,
                              hipStream_t stream) {
  const float* obs         = (const float*)d_in[0];
  const float* beta_logits = (const float*)d_in[1];
  const float* pi_logits   = (const float*)d_in[2];
  const float* means       = (const float*)d_in[3];
  const float* log_vars    = (const float*)d_in[4];
  float* out = (float*)d_out;
  float* ws  = (float*)d_ws;   // ~25.3 MB, confirmed available

  hipLaunchKernelGGL(prep_kernel, dim3(1), dim3(64), 0, stream,
                     beta_logits, pi_logits, means, log_vars, ws);
  hipLaunchKernelGGL(emis_kernel, dim3((Tn*5 + 255)/256), dim3(256), 0, stream, obs, ws);
  hipLaunchKernelGGL(scan2_kernel, dim3(2*NBS), dim3(128), 0, stream, ws, out);
  hipLaunchKernelGGL(combine2_kernel, dim3(1), dim3(128), 0, stream, ws, out);
  hipLaunchKernelGGL(scale2_kernel, dim3(2*NBS), dim3(128), 0, stream, ws, out);
}

// Round 5
// 137.689 us; speedup vs baseline: 3.1692x; 1.4596x over previous
//
#include <hip/hip_runtime.h>

// HDP-HMM forward-backward, exact-semantics parallel decomposition. R5:
//  - emis_kernel rewritten: LDS-staged obs tile + constants (padded, conflict-free),
//    removes the scattered-global-load latency stall (was 80us at 9% VALU)
//  - Wn 48->24 (bit-identical absmax at 96 and 48 => tau<0.4 => err<1e-9)

namespace {
constexpr int Tn = 262144;
constexpr int Kn = 20;
constexpr int Fn = 16;
constexpr float EPSF = 1e-10f;
constexpr float TINY = 1e-35f;

constexpr int Ln2 = 64;
constexpr int Wn2 = 24;
constexpr int NC2 = Tn / Ln2;          // 4096 chunks per direction
constexpr int NBS = NC2 / 4;           // 1024 blocks per direction (4 chunks/block)

// ws layout (floats); ~25.3 MB
constexpr size_t OFF_P    = 0;                   // P row-major [400]
constexpr size_t OFF_W    = 400;                 // stick weights [20]
constexpr size_t OFF_CK   = 420;                 // emission const [20]
constexpr size_t OFF_MVIV = 440;                 // float2 (mean*iv, iv) [640]
constexpr size_t OFF_E    = 1152;                // E[t*20+k] [Tn*20 + 64 pad]
constexpr size_t OFF_MSF  = OFF_E + (size_t)Tn*20 + 64;   // float2[Tn] fwd (m, 1/sigma)
constexpr size_t OFF_MSB  = OFF_MSF + 2*(size_t)Tn;       // float2[Tn] bwd
constexpr size_t OFF_MATF = OFF_MSB + 2*(size_t)Tn;       // [NC2][4]
constexpr size_t OFF_MATB = OFF_MATF + 4*(size_t)NC2;
constexpr size_t OFF_SF   = OFF_MATB + 4*(size_t)NC2;     // [NC2]
constexpr size_t OFF_SB   = OFF_SF + NC2;                 // [NC2]
constexpr size_t OFF_END  = OFF_SB + NC2;
}

#if __has_builtin(__builtin_amdgcn_rcpf)
#define FRCP(x) __builtin_amdgcn_rcpf(x)
#else
#define FRCP(x) (1.0f/(x))
#endif

template<int CTRL>
__device__ __forceinline__ float dpp_add(float v) {
  int s = __builtin_amdgcn_update_dpp(0, __float_as_int(v), CTRL, 0xF, 0xF, true);
  return v + __int_as_float(s);
}

// Sum across each 32-lane half, broadcast to all lanes of the half.
__device__ __forceinline__ float reduce32b(float v) {
  v = dpp_add<0xB1>(v);     // xor1 (quad_perm 1,0,3,2)
  v = dpp_add<0x4E>(v);     // xor2 (quad_perm 2,3,0,1)
  v = dpp_add<0x141>(v);    // row_half_mirror == xor4 once quads uniform
  v = dpp_add<0x140>(v);    // row_mirror == xor8 once octs uniform
  int x = __builtin_amdgcn_ds_swizzle(__float_as_int(v), 0x401F);  // xor16
  return v + __int_as_float(x);
}

// ============================ prep ============================
__global__ __launch_bounds__(64) void prep_kernel(
    const float* beta_logits, const float* pi_logits,
    const float* means, const float* log_vars, float* ws)
{
  int k = threadIdx.x;
  if (k < Kn) {
    float row[Kn];
    float mx = -1e30f;
#pragma unroll
    for (int j = 0; j < Kn; ++j) { row[j] = pi_logits[k*Kn + j]; mx = fmaxf(mx, row[j]); }
    float s = 0.f;
#pragma unroll
    for (int j = 0; j < Kn; ++j) { row[j] = expf(row[j] - mx); s += row[j]; }
    float invs = 1.0f / s;
#pragma unroll
    for (int j = 0; j < Kn; ++j) ws[OFF_P + k*Kn + j] = row[j] * invs;
    float ck = 0.f;
#pragma unroll
    for (int f = 0; f < Fn; ++f) {
      float lv  = log_vars[k*Fn + f];
      float var = expf(lv) + 1e-6f;
      float iv  = 1.0f / var;
      float mu  = means[k*Fn + f];
      ((float2*)(ws + OFF_MVIV))[k*Fn + f] = make_float2(mu * iv, iv);
      ck += mu*mu*iv + logf(6.2831853071795864f * var);
    }
    ws[OFF_CK + k] = ck;
  } else if (k == Kn) {
    float cp = 1.f;
#pragma unroll
    for (int i = 0; i < Kn; ++i) {
      float b = 1.0f / (1.0f + expf(-beta_logits[i]));
      ws[OFF_W + i] = b * cp;
      cp *= (1.0f - b);
    }
  }
}

// ============================ emission ============================
// Block = 320 threads = 64 t-rows x 5 threads (4 k each).
// Stage obs tile + constants in LDS (padded for bank-conflict-free b128 reads);
// all compute fed from LDS; float4 coalesced store.
__global__ __launch_bounds__(320) void emis_kernel(const float* __restrict__ obs, float* ws)
{
  __shared__ __align__(16) float so[64][20];    // obs tile, row-pad 16->20
  __shared__ __align__(16) float scm[16][24];   // mean*iv, [f][k] pad 20->24
  __shared__ __align__(16) float scv[16][24];   // iv
  __shared__ __align__(16) float sck[20];
  const int tid = threadIdx.x;
  const int t0 = blockIdx.x * 64;

  if (tid < 256) {
    // 64 rows x 16 floats = 256 float4, perfectly coalesced
    float4 v = ((const float4*)(obs + (size_t)t0 * Fn))[tid];
    int r = tid >> 2, j = tid & 3;
    *(float4*)&so[r][j*4] = v;
  } else {
    int i = tid - 256;                 // 0..63 (one wave)
#pragma unroll
    for (int q = 0; q < 5; ++q) {
      int idx = i * 5 + q;             // 0..319 = k*16+f
      float2 c2 = ((const float2*)(ws + OFF_MVIV))[idx];
      int k = idx >> 4, f = idx & 15;
      scm[f][k] = c2.x;
      scv[f][k] = c2.y;
    }
    if (i < Kn) sck[i] = ws[OFF_CK + i];
  }
  __syncthreads();

  const int tl = tid / 5;
  const int k0 = (tid - tl*5) * 4;

  float o[16];
  *(float4*)&o[0]  = *(const float4*)&so[tl][0];
  *(float4*)&o[4]  = *(const float4*)&so[tl][4];
  *(float4*)&o[8]  = *(const float4*)&so[tl][8];
  *(float4*)&o[12] = *(const float4*)&so[tl][12];

  float s1x=0.f,s1y=0.f,s1z=0.f,s1w=0.f;
  float s2x=0.f,s2y=0.f,s2z=0.f,s2w=0.f;
#pragma unroll
  for (int f = 0; f < Fn; ++f) {
    float4 cm = *(const float4*)&scm[f][k0];
    float4 cv = *(const float4*)&scv[f][k0];
    float ov = o[f];
    s1x = fmaf(cv.x * ov, ov, s1x); s2x = fmaf(cm.x, ov, s2x);
    s1y = fmaf(cv.y * ov, ov, s1y); s2y = fmaf(cm.y, ov, s2y);
    s1z = fmaf(cv.z * ov, ov, s1z); s2z = fmaf(cm.z, ov, s2z);
    s1w = fmaf(cv.w * ov, ov, s1w); s2w = fmaf(cm.w, ov, s2w);
  }
  float4 ckv = *(const float4*)&sck[k0];
  float4 rr;
  rr.x = __expf(fmaf(-0.5f, s1x + ckv.x, s2x));
  rr.y = __expf(fmaf(-0.5f, s1y + ckv.y, s2y));
  rr.z = __expf(fmaf(-0.5f, s1z + ckv.z, s2z));
  rr.w = __expf(fmaf(-0.5f, s1w + ckv.w, s2w));
  *(float4*)(ws + OFF_E + (size_t)(t0 + tl)*20 + k0) = rr;
}

// ============================ scan ============================
__global__ __launch_bounds__(128) void scan2_kernel(float* ws, float* out)
{
  __shared__ float4 xsh4[4][8];
  const int tid = threadIdx.x;
  const int g   = tid >> 5;
  const int jj  = tid & 31;
  const bool act = (jj < Kn);
  const float vReset = act ? 0.05f : 0.f;
  const bool isF = ((int)blockIdx.x < NBS);
  const int c = (isF ? (int)blockIdx.x : (int)blockIdx.x - NBS) * 4 + g;
  const float* E = ws + OFF_E;
  float* xg = (float*)&xsh4[g][0];

  float Pv[Kn];
#pragma unroll
  for (int k = 0; k < Kn; ++k)
    Pv[k] = act ? (isF ? ws[OFF_P + k*Kn + jj] : ws[OFF_P + jj*Kn + k]) : 0.f;

  float Ma = 1.f, Mc = 0.f, Md = 1.f;
  float2* msig = (float2*)(ws + (isF ? OFF_MSF : OFF_MSB));
  float* uOut = out + (isF ? (size_t)0 : (size_t)Tn * Kn);

  auto mobius = [&](float m) {
    float na = m * Ma;
    float nc = fmaf(EPSF, Mc, na);
    float nd = EPSF * Md;
    float mx = fmaxf(nc, nd);
    float lam = (mx > 0.f) ? FRCP(mx) : 1.0f;
    Ma = na*lam; Mc = nc*lam; Md = nd*lam;
  };
  auto matvec = [&]() -> float {
    float4 x0 = xsh4[g][0], x1 = xsh4[g][1], x2 = xsh4[g][2],
           x3 = xsh4[g][3], x4 = xsh4[g][4];
    float a0 = x0.x*Pv[0], a1 = x0.y*Pv[1], a2 = x0.z*Pv[2], a3 = x0.w*Pv[3];
    a0 = fmaf(x1.x, Pv[4], a0); a1 = fmaf(x1.y, Pv[5], a1);
    a2 = fmaf(x1.z, Pv[6], a2); a3 = fmaf(x1.w, Pv[7], a3);
    a0 = fmaf(x2.x, Pv[8], a0); a1 = fmaf(x2.y, Pv[9], a1);
    a2 = fmaf(x2.z, Pv[10], a2); a3 = fmaf(x2.w, Pv[11], a3);
    a0 = fmaf(x3.x, Pv[12], a0); a1 = fmaf(x3.y, Pv[13], a1);
    a2 = fmaf(x3.z, Pv[14], a2); a3 = fmaf(x3.w, Pv[15], a3);
    a0 = fmaf(x4.x, Pv[16], a0); a1 = fmaf(x4.y, Pv[17], a1);
    a2 = fmaf(x4.z, Pv[18], a2); a3 = fmaf(x4.w, Pv[19], a3);
    return (a0+a1) + (a2+a3);
  };

  if (isF) {
    const int bodyStart = c * Ln2;
    const int tend = bodyStart + Ln2 - 1;
    const int t0 = (c == 0) ? 0 : (bodyStart - Wn2);
    float wj = act ? ws[OFF_W + jj] : 0.f;
    float e0 = E[t0*20 + jj];
    float v = act ? ((c == 0) ? wj * e0 : 0.05f * e0) : 0.f;
    float sv = reduce32b(v);
    float m = sv;                               // A_prev = 1
    float iV = (sv > TINY) ? FRCP(sv) : 1.0f;
    if (sv <= TINY) v = vReset;
    if (c == 0) {
      if (jj == 0) msig[0] = make_float2(m, iV);
      mobius(m);
      if (act) uOut[jj] = v;
    }
    float A = m * iV;
    float rho = (m > TINY) ? FRCP(m) : 1.0f;
    float e1 = E[(t0+1)*20 + jj];
    float e2 = E[(t0+2)*20 + jj];
    float e3 = E[(t0+3)*20 + jj];

#define FWD_STEP(REC)                                                     \
    {                                                                     \
      xg[jj] = v;                                                         \
      float acc = matvec();                                               \
      float er = e1 * rho;                                                \
      e1 = e2; e2 = e3; e3 = E[(t+3)*20 + jj];                            \
      v = acc * er;                                                       \
      float sv2 = reduce32b(v);                                           \
      float mn = sv2 * A;                                                 \
      float iVn = (sv2 > TINY) ? FRCP(sv2) : 1.0f;                        \
      if (sv2 <= TINY) v = vReset;                                        \
      if (REC) {                                                          \
        if (jj == 0) msig[t] = make_float2(mn, iVn);                      \
        mobius(mn);                                                       \
        if (act) uOut[(size_t)t*Kn + jj] = v;                             \
      }                                                                   \
      A = mn * iVn;                                                       \
      rho = (mn > TINY) ? FRCP(mn) : 1.0f;                                \
    }

    for (int t = t0 + 1; t < bodyStart; ++t) FWD_STEP(false)
    const int bstart2 = (c == 0) ? 1 : bodyStart;
    for (int t = bstart2; t <= tend; ++t) FWD_STEP(true)
#undef FWD_STEP
    if (jj == 0) ((float4*)(ws + OFF_MATF))[c] = make_float4(Ma, Mc, Md, 0.f);
  } else {
    const int bodyStart = c * Ln2;
    const int top = bodyStart + Ln2 - 1;
    int r0 = top + Wn2; if (r0 > Tn - 1) r0 = Tn - 1;   // r0==Tn-1 => exact init
    float v = vReset;                                   // uniform direction
    float sv = reduce32b(v);                            // ~1.0
    float iV = (sv > TINY) ? FRCP(sv) : 1.0f;
    float A = iV;                                       // m_prev = 1 convention
    float rho = 1.0f;
    float e1 = E[r0*20 + jj];
    float e2 = E[(r0-1)*20 + jj];
    float e3 = E[(r0-2)*20 + jj];

#define BWD_STEP(REC)                                                     \
    {                                                                     \
      xg[jj] = v * e1;                                                    \
      float acc = matvec();                                               \
      v = acc * rho;                                                      \
      e1 = e2; e2 = e3; e3 = E[(r-2)*20 + jj];                            \
      float sv2 = reduce32b(v);                                           \
      float mn = sv2 * A;                                                 \
      float iVn = (sv2 > TINY) ? FRCP(sv2) : 1.0f;                        \
      if (sv2 <= TINY) v = vReset;                                        \
      if (REC) {                                                          \
        if (jj == 0) msig[r+1] = make_float2(mn, iVn);                    \
        mobius(mn);                                                       \
        if (act) uOut[(size_t)r*Kn + jj] = v;                             \
      }                                                                   \
      A = mn * iVn;                                                       \
      rho = (mn > TINY) ? FRCP(mn) : 1.0f;                                \
    }

    for (int r = r0 - 1; r > top; --r) BWD_STEP(false)
    int rb = (r0 - 1 < top) ? (r0 - 1) : top;
    for (int r = rb; r >= bodyStart; --r) BWD_STEP(true)
#undef BWD_STEP
    if (jj == 0) ((float4*)(ws + OFF_MATB))[NC2 - 1 - c] = make_float4(Ma, Mc, Md, 0.f);
  }
}

// ============================ combine ============================
__global__ __launch_bounds__(128) void combine2_kernel(float* ws, float* out)
{
  const int wid  = threadIdx.x >> 6;
  const int lane = threadIdx.x & 63;
  const float4* M4 = (const float4*)(ws + (wid == 0 ? OFF_MATF : OFF_MATB));
  float* sArr = ws + (wid == 0 ? OFF_SF : OFF_SB);
  const float s0 = (wid == 0) ? 1.0f : 20.0f;
  constexpr int PG = NC2 / 64;   // 64

  float a = 1.f, cc = 0.f, d = 1.f;
#pragma unroll 4
  for (int i = 0; i < PG; ++i) {
    float4 mm = M4[lane*PG + i];
    float na = mm.x * a;
    float nc = fmaf(mm.y, a, mm.z * cc);
    float nd = mm.z * d;
    float mx = fmaxf(na, fmaxf(nc, nd));
    float lam = (mx > 0.f) ? (1.0f/mx) : 1.0f;
    a = na*lam; cc = nc*lam; d = nd*lam;
  }
  float ia = a, ic = cc, id = d;
  for (int off = 1; off < 64; off <<= 1) {
    float pa = __shfl_up(ia, off, 64);
    float pc = __shfl_up(ic, off, 64);
    float pd = __shfl_up(id, off, 64);
    if (lane >= off) {
      float na = ia * pa;
      float nc = fmaf(ic, pa, id * pc);
      float nd = id * pd;
      float mx = fmaxf(na, fmaxf(nc, nd));
      float lam = (mx > 0.f) ? (1.0f/mx) : 1.0f;
      ia = na*lam; ic = nc*lam; id = nd*lam;
    }
  }
  if (wid == 0 && lane == 63) {
    float den = fmaf(ic, s0, id);
    float sfin = (den > 0.f) ? (ia * s0)/den : 0.f;
    out[(size_t)2 * Tn * Kn] = logf(sfin + EPSF);
  }
  float ea = __shfl_up(ia, 1, 64);
  float ec = __shfl_up(ic, 1, 64);
  float ed = __shfl_up(id, 1, 64);
  if (lane == 0) { ea = 1.f; ec = 0.f; ed = 1.f; }
  float s;
  { float num = ea * s0; float den = fmaf(ec, s0, ed);
    s = (den > 0.f) ? num/den : 0.f; }
#pragma unroll 4
  for (int i = 0; i < PG; ++i) {
    sArr[lane*PG + i] = s;
    float4 mm = M4[lane*PG + i];
    float num = mm.x * s; float den = fmaf(mm.y, s, mm.z);
    s = (den > 0.f) ? num/den : 0.f;
  }
}

// ============================ scale ============================
// Phase 1: per chunk, serial sigma chain into LDS. Phase 2: coalesced float4 RMW.
__global__ __launch_bounds__(128) void scale2_kernel(float* ws, float* out)
{
  __shared__ float sig[4][Ln2];
  const int tid = threadIdx.x;
  const int g   = tid >> 5;
  const int jj  = tid & 31;
  const bool isF = ((int)blockIdx.x < NBS);
  const int c = (isF ? (int)blockIdx.x : (int)blockIdx.x - NBS) * 4 + g;
  constexpr int QPC = Ln2 * Kn / 4;   // float4 quads per chunk = 320

  if (isF) {
    const float2* msig = (const float2*)(ws + OFF_MSF);
    float s = ws[OFF_SF + c];
    const int t0 = c * Ln2;
    for (int i = 0; i < Ln2; ++i) {
      float2 p = msig[t0 + i];
      float z = s * p.x;
      float sn = z * FRCP(z + EPSF);
      if (jj == 0) sig[g][i] = sn * p.y;
      s = sn;
    }
    __syncthreads();
    float4* A4 = (float4*)out + (size_t)c * QPC;
#pragma unroll
    for (int i = jj; i < QPC; i += 32) {
      int tl = i / 5;
      float sg = sig[g][tl];
      float4 v = A4[i];
      v.x *= sg; v.y *= sg; v.z *= sg; v.w *= sg;
      A4[i] = v;
    }
  } else {
    const float2* msig = (const float2*)(ws + OFF_MSB);
    const int slot = NC2 - 1 - c;
    float s = ws[OFF_SB + slot];
    const int bodyStart = c * Ln2;
    const int top = bodyStart + Ln2 - 1;
    const bool lastChunk = (c == NC2 - 1);
    for (int r = top; r >= bodyStart; --r) {
      if (r == Tn - 1) {
        if (jj == 0) sig[g][Ln2 - 1] = 1.0f;   // placeholder, overridden below
        continue;
      }
      float2 p = msig[r + 1];
      float z = s * p.x;
      float sn = z * FRCP(z + EPSF);
      if (jj == 0) sig[g][r - bodyStart] = sn * p.y;
      s = sn;
    }
    __syncthreads();
    float4* B4 = (float4*)out + ((size_t)Tn * Kn) / 4 + (size_t)c * QPC;
#pragma unroll
    for (int i = jj; i < QPC; i += 32) {
      int tl = i / 5;
      if (lastChunk && tl == Ln2 - 1) {
        B4[i] = make_float4(1.f, 1.f, 1.f, 1.f);   // beta[T-1] = ones exactly
      } else {
        float sg = sig[g][tl];
        float4 v = B4[i];
        v.x *= sg; v.y *= sg; v.z *= sg; v.w *= sg;
        B4[i] = v;
      }
    }
  }
}

extern "C" void kernel_launch(void* const* d_in, const int* in_sizes, int n_in,
                              void* d_out, int out_size, void* d_ws, size_t ws_size,
                              hipStream_t stream) {
  const float* obs         = (const float*)d_in[0];
  const float* beta_logits = (const float*)d_in[1];
  const float* pi_logits   = (const float*)d_in[2];
  const float* means       = (const float*)d_in[3];
  const float* log_vars    = (const float*)d_in[4];
  float* out = (float*)d_out;
  float* ws  = (float*)d_ws;   // ~25.3 MB, confirmed available

  hipLaunchKernelGGL(prep_kernel, dim3(1), dim3(64), 0, stream,
                     beta_logits, pi_logits, means, log_vars, ws);
  hipLaunchKernelGGL(emis_kernel, dim3(Tn/64), dim3(320), 0, stream, obs, ws);
  hipLaunchKernelGGL(scan2_kernel, dim3(2*NBS), dim3(128), 0, stream, ws, out);
  hipLaunchKernelGGL(combine2_kernel, dim3(1), dim3(128), 0, stream, ws, out);
  hipLaunchKernelGGL(scale2_kernel, dim3(2*NBS), dim3(128), 0, stream, ws, out);
}

// Round 6
// 135.240 us; speedup vs baseline: 3.2266x; 1.0181x over previous
//
#include <hip/hip_runtime.h>

// HDP-HMM forward-backward, exact-semantics parallel decomposition. R6:
//  - scan groups 32->16 lanes (lane l owns states l and 16+l): reduce is pure DPP
//    (no ds_swizzle on the critical path), 4 chunks per wave, 16 chunks/SIMD
//  - Ln=32, Wn=20 -> 52 steps/chunk, 8192 chunks/dir, all waves co-resident
//  - iV folded into stored u (v*iVn off the carried path): msig float2->float,
//    ws shrinks to 23.4 MB, scale applies a single mul

namespace {
constexpr int Tn = 262144;
constexpr int Kn = 20;
constexpr int Fn = 16;
constexpr float EPSF = 1e-10f;
constexpr float TINY = 1e-35f;

constexpr int Ln3 = 32;
constexpr int Wn3 = 20;
constexpr int NC3 = Tn / Ln3;          // 8192 chunks per direction
constexpr int NBF = NC3 / 16;          // 512 scan blocks per direction (16 chunks/block)
constexpr int NBS3 = NC3 / 4;          // 2048 scale blocks per direction

// ws layout (floats); total 5,850,304 floats = 23.4 MB (< proven-available 25.3 MB)
constexpr size_t OFF_P    = 0;                   // P row-major [400]
constexpr size_t OFF_W    = 400;                 // stick weights [20]
constexpr size_t OFF_CK   = 420;                 // emission const [20]
constexpr size_t OFF_MVIV = 440;                 // float2 (mean*iv, iv) [640]
constexpr size_t OFF_E    = 1152;                // E[t*20+k] [Tn*20 + 64 pad]
constexpr size_t OFF_MF   = OFF_E + (size_t)Tn*20 + 64;   // m_t fwd [Tn]
constexpr size_t OFF_MB   = OFF_MF + (size_t)Tn;          // m'_t bwd [Tn]
constexpr size_t OFF_MATF = OFF_MB + (size_t)Tn;          // [NC3][4]
constexpr size_t OFF_MATB = OFF_MATF + 4*(size_t)NC3;
constexpr size_t OFF_SF   = OFF_MATB + 4*(size_t)NC3;     // [NC3]
constexpr size_t OFF_SB   = OFF_SF + NC3;                 // [NC3]
constexpr size_t OFF_END  = OFF_SB + NC3;
}

#if __has_builtin(__builtin_amdgcn_rcpf)
#define FRCP(x) __builtin_amdgcn_rcpf(x)
#else
#define FRCP(x) (1.0f/(x))
#endif

template<int CTRL>
__device__ __forceinline__ float dpp_add(float v) {
  int s = __builtin_amdgcn_update_dpp(0, __float_as_int(v), CTRL, 0xF, 0xF, true);
  return v + __int_as_float(s);
}

// Sum across each 16-lane row, broadcast to all lanes of the row. Pure DPP.
__device__ __forceinline__ float reduce16(float v) {
  v = dpp_add<0xB1>(v);     // xor1 (quad_perm 1,0,3,2)
  v = dpp_add<0x4E>(v);     // xor2 (quad_perm 2,3,0,1)
  v = dpp_add<0x141>(v);    // row_half_mirror == xor4 once quads uniform
  v = dpp_add<0x140>(v);    // row_mirror == xor8 once octs uniform
  return v;
}

// ============================ prep ============================
__global__ __launch_bounds__(64) void prep_kernel(
    const float* beta_logits, const float* pi_logits,
    const float* means, const float* log_vars, float* ws)
{
  int k = threadIdx.x;
  if (k < Kn) {
    float row[Kn];
    float mx = -1e30f;
#pragma unroll
    for (int j = 0; j < Kn; ++j) { row[j] = pi_logits[k*Kn + j]; mx = fmaxf(mx, row[j]); }
    float s = 0.f;
#pragma unroll
    for (int j = 0; j < Kn; ++j) { row[j] = expf(row[j] - mx); s += row[j]; }
    float invs = 1.0f / s;
#pragma unroll
    for (int j = 0; j < Kn; ++j) ws[OFF_P + k*Kn + j] = row[j] * invs;
    float ck = 0.f;
#pragma unroll
    for (int f = 0; f < Fn; ++f) {
      float lv  = log_vars[k*Fn + f];
      float var = expf(lv) + 1e-6f;
      float iv  = 1.0f / var;
      float mu  = means[k*Fn + f];
      ((float2*)(ws + OFF_MVIV))[k*Fn + f] = make_float2(mu * iv, iv);
      ck += mu*mu*iv + logf(6.2831853071795864f * var);
    }
    ws[OFF_CK + k] = ck;
  } else if (k == Kn) {
    float cp = 1.f;
#pragma unroll
    for (int i = 0; i < Kn; ++i) {
      float b = 1.0f / (1.0f + expf(-beta_logits[i]));
      ws[OFF_W + i] = b * cp;
      cp *= (1.0f - b);
    }
  }
}

// ============================ emission ============================
__global__ __launch_bounds__(320) void emis_kernel(const float* __restrict__ obs, float* ws)
{
  __shared__ __align__(16) float so[64][20];
  __shared__ __align__(16) float scm[16][24];
  __shared__ __align__(16) float scv[16][24];
  __shared__ __align__(16) float sck[20];
  const int tid = threadIdx.x;
  const int t0 = blockIdx.x * 64;

  if (tid < 256) {
    float4 v = ((const float4*)(obs + (size_t)t0 * Fn))[tid];
    int r = tid >> 2, j = tid & 3;
    *(float4*)&so[r][j*4] = v;
  } else {
    int i = tid - 256;
#pragma unroll
    for (int q = 0; q < 5; ++q) {
      int idx = i * 5 + q;
      float2 c2 = ((const float2*)(ws + OFF_MVIV))[idx];
      int k = idx >> 4, f = idx & 15;
      scm[f][k] = c2.x;
      scv[f][k] = c2.y;
    }
    if (i < Kn) sck[i] = ws[OFF_CK + i];
  }
  __syncthreads();

  const int tl = tid / 5;
  const int k0 = (tid - tl*5) * 4;

  float o[16];
  *(float4*)&o[0]  = *(const float4*)&so[tl][0];
  *(float4*)&o[4]  = *(const float4*)&so[tl][4];
  *(float4*)&o[8]  = *(const float4*)&so[tl][8];
  *(float4*)&o[12] = *(const float4*)&so[tl][12];

  float s1x=0.f,s1y=0.f,s1z=0.f,s1w=0.f;
  float s2x=0.f,s2y=0.f,s2z=0.f,s2w=0.f;
#pragma unroll
  for (int f = 0; f < Fn; ++f) {
    float4 cm = *(const float4*)&scm[f][k0];
    float4 cv = *(const float4*)&scv[f][k0];
    float ov = o[f];
    s1x = fmaf(cv.x * ov, ov, s1x); s2x = fmaf(cm.x, ov, s2x);
    s1y = fmaf(cv.y * ov, ov, s1y); s2y = fmaf(cm.y, ov, s2y);
    s1z = fmaf(cv.z * ov, ov, s1z); s2z = fmaf(cm.z, ov, s2z);
    s1w = fmaf(cv.w * ov, ov, s1w); s2w = fmaf(cm.w, ov, s2w);
  }
  float4 ckv = *(const float4*)&sck[k0];
  float4 rr;
  rr.x = __expf(fmaf(-0.5f, s1x + ckv.x, s2x));
  rr.y = __expf(fmaf(-0.5f, s1y + ckv.y, s2y));
  rr.z = __expf(fmaf(-0.5f, s1z + ckv.z, s2z));
  rr.w = __expf(fmaf(-0.5f, s1w + ckv.w, s2w));
  *(float4*)(ws + OFF_E + (size_t)(t0 + tl)*20 + k0) = rr;
}

// ============================ scan ============================
// 16-lane groups: lane l owns state l, and state 16+l for l<4.
// Block = 256 threads = 16 groups; fwd blocks [0,NBF), bwd [NBF,2*NBF).
__global__ __launch_bounds__(256, 4) void scan3_kernel(float* ws, float* out)
{
  __shared__ __align__(16) float xsh[16][20];
  const int tid = threadIdx.x;
  const int g   = tid >> 4;
  const int ll  = tid & 15;
  const bool hi = (ll < 4);
  const int l4  = 16 + (ll & 3);
  const bool isF = ((int)blockIdx.x < NBF);
  const int c = (isF ? (int)blockIdx.x : (int)blockIdx.x - NBF) * 16 + g;
  const float* E = ws + OFF_E;
  float* xg = &xsh[g][0];

  float Pv0[Kn], Pv1[Kn];
#pragma unroll
  for (int k = 0; k < Kn; ++k) {
    if (isF) {
      Pv0[k] = ws[OFF_P + k*Kn + ll];
      float p1 = ws[OFF_P + k*Kn + l4];
      Pv1[k] = hi ? p1 : 0.f;
    } else {
      Pv0[k] = ws[OFF_P + ll*Kn + k];
      float p1 = ws[OFF_P + l4*Kn + k];
      Pv1[k] = hi ? p1 : 0.f;
    }
  }

  float Ma = 1.f, Mc = 0.f, Md = 1.f;
  float* mArr = ws + (isF ? OFF_MF : OFF_MB);
  float* uOut = out + (isF ? (size_t)0 : (size_t)Tn * Kn);

  auto mobius = [&](float m) {
    float na = m * Ma;
    float nc = fmaf(EPSF, Mc, na);
    float nd = EPSF * Md;
    float mx = fmaxf(nc, nd);
    float lam = (mx > 0.f) ? FRCP(mx) : 1.0f;
    Ma = na*lam; Mc = nc*lam; Md = nd*lam;
  };
  auto matvec2 = [&](float& r0, float& r1) {
    float xv[20];
    *(float4*)&xv[0]  = *(const float4*)&xg[0];
    *(float4*)&xv[4]  = *(const float4*)&xg[4];
    *(float4*)&xv[8]  = *(const float4*)&xg[8];
    *(float4*)&xv[12] = *(const float4*)&xg[12];
    *(float4*)&xv[16] = *(const float4*)&xg[16];
    float A0 = xv[0]*Pv0[0], A1 = xv[1]*Pv0[1];
    float B0 = xv[0]*Pv1[0], B1 = xv[1]*Pv1[1];
#pragma unroll
    for (int k = 2; k < 20; k += 2) {
      A0 = fmaf(xv[k],   Pv0[k],   A0);
      A1 = fmaf(xv[k+1], Pv0[k+1], A1);
      B0 = fmaf(xv[k],   Pv1[k],   B0);
      B1 = fmaf(xv[k+1], Pv1[k+1], B1);
    }
    r0 = A0 + A1; r1 = B0 + B1;
  };

  if (isF) {
    const int bodyStart = c * Ln3;
    const int tend = bodyStart + Ln3 - 1;
    const int t0 = (c == 0) ? 0 : (bodyStart - Wn3);
    float e0a = E[t0*20 + ll],     e1a = E[t0*20 + l4];
    float v0, v1;
    if (c == 0) {
      v0 = ws[OFF_W + ll] * e0a;
      v1 = hi ? ws[OFF_W + l4] * e1a : 0.f;
    } else {
      v0 = 0.05f * e0a;
      v1 = hi ? 0.05f * e1a : 0.f;
    }
    float sv = reduce16(v0 + v1);
    float m = sv;
    float iV = (sv > TINY) ? FRCP(sv) : 1.0f;
    if (sv <= TINY) { v0 = 0.05f; v1 = hi ? 0.05f : 0.f; }
    if (c == 0) {
      if (ll == 0) mArr[0] = m;
      mobius(m);
      uOut[ll] = v0 * iV;
      if (hi) uOut[l4] = v1 * iV;
    }
    float A = m * iV;
    float rho = (m > TINY) ? FRCP(m) : 1.0f;
    float e0b = E[(t0+1)*20 + ll], e1b = E[(t0+1)*20 + l4];
    float e0c = E[(t0+2)*20 + ll], e1c = E[(t0+2)*20 + l4];

#define FWD_STEP(REC)                                                     \
    {                                                                     \
      xg[ll] = v0;                                                        \
      if (hi) xg[16 + ll] = v1;                                           \
      float acc0, acc1; matvec2(acc0, acc1);                              \
      float er0 = e0a * rho, er1 = e1a * rho;                             \
      e0a = e0b; e0b = e0c; e0c = E[(t+3)*20 + ll];                       \
      e1a = e1b; e1b = e1c; e1c = E[(t+3)*20 + l4];                       \
      v0 = acc0 * er0; v1 = acc1 * er1;                                   \
      float sv2 = reduce16(v0 + v1);                                      \
      float mn = sv2 * A;                                                 \
      float iVn = (sv2 > TINY) ? FRCP(sv2) : 1.0f;                        \
      if (sv2 <= TINY) { v0 = 0.05f; v1 = hi ? 0.05f : 0.f; }             \
      if (REC) {                                                          \
        if (ll == 0) mArr[t] = mn;                                        \
        mobius(mn);                                                       \
        uOut[(size_t)t*Kn + ll] = v0 * iVn;                               \
        if (hi) uOut[(size_t)t*Kn + 16 + ll] = v1 * iVn;                  \
      }                                                                   \
      A = mn * iVn;                                                       \
      rho = (mn > TINY) ? FRCP(mn) : 1.0f;                                \
    }

    for (int t = t0 + 1; t < bodyStart; ++t) FWD_STEP(false)
    const int bstart2 = (c == 0) ? 1 : bodyStart;
    for (int t = bstart2; t <= tend; ++t) FWD_STEP(true)
#undef FWD_STEP
    if (ll == 0) ((float4*)(ws + OFF_MATF))[c] = make_float4(Ma, Mc, Md, 0.f);
  } else {
    const int bodyStart = c * Ln3;
    const int top = bodyStart + Ln3 - 1;
    int r0 = top + Wn3; if (r0 > Tn - 1) r0 = Tn - 1;   // r0==Tn-1 => exact init
    float v0 = 0.05f, v1 = hi ? 0.05f : 0.f;
    float sv = reduce16(v0 + v1);                        // ~1.0
    float iV = (sv > TINY) ? FRCP(sv) : 1.0f;
    float A = iV;
    float rho = 1.0f;
    float e0a = E[r0*20 + ll],     e1a = E[r0*20 + l4];
    float e0b = E[(r0-1)*20 + ll], e1b = E[(r0-1)*20 + l4];
    float e0c = E[(r0-2)*20 + ll], e1c = E[(r0-2)*20 + l4];

#define BWD_STEP(REC)                                                     \
    {                                                                     \
      xg[ll] = v0 * e0a;                                                  \
      if (hi) xg[16 + ll] = v1 * e1a;                                     \
      float acc0, acc1; matvec2(acc0, acc1);                              \
      v0 = acc0 * rho; v1 = acc1 * rho;                                   \
      e0a = e0b; e0b = e0c; e0c = E[(r-2)*20 + ll];                       \
      e1a = e1b; e1b = e1c; e1c = E[(r-2)*20 + l4];                       \
      float sv2 = reduce16(v0 + v1);                                      \
      float mn = sv2 * A;                                                 \
      float iVn = (sv2 > TINY) ? FRCP(sv2) : 1.0f;                        \
      if (sv2 <= TINY) { v0 = 0.05f; v1 = hi ? 0.05f : 0.f; }             \
      if (REC) {                                                          \
        if (ll == 0) mArr[r+1] = mn;                                      \
        mobius(mn);                                                       \
        uOut[(size_t)r*Kn + ll] = v0 * iVn;                               \
        if (hi) uOut[(size_t)r*Kn + 16 + ll] = v1 * iVn;                  \
      }                                                                   \
      A = mn * iVn;                                                       \
      rho = (mn > TINY) ? FRCP(mn) : 1.0f;                                \
    }

    for (int r = r0 - 1; r > top; --r) BWD_STEP(false)
    int rb = (r0 - 1 < top) ? (r0 - 1) : top;
    for (int r = rb; r >= bodyStart; --r) BWD_STEP(true)
#undef BWD_STEP
    if (ll == 0) ((float4*)(ws + OFF_MATB))[NC3 - 1 - c] = make_float4(Ma, Mc, Md, 0.f);
  }
}

// ============================ combine ============================
__global__ __launch_bounds__(128) void combine3_kernel(float* ws, float* out)
{
  const int wid  = threadIdx.x >> 6;
  const int lane = threadIdx.x & 63;
  const float4* M4 = (const float4*)(ws + (wid == 0 ? OFF_MATF : OFF_MATB));
  float* sArr = ws + (wid == 0 ? OFF_SF : OFF_SB);
  const float s0 = (wid == 0) ? 1.0f : 20.0f;
  constexpr int PG = NC3 / 64;   // 128

  float a = 1.f, cc = 0.f, d = 1.f;
#pragma unroll 4
  for (int i = 0; i < PG; ++i) {
    float4 mm = M4[lane*PG + i];
    float na = mm.x * a;
    float nc = fmaf(mm.y, a, mm.z * cc);
    float nd = mm.z * d;
    float mx = fmaxf(na, fmaxf(nc, nd));
    float lam = (mx > 0.f) ? (1.0f/mx) : 1.0f;
    a = na*lam; cc = nc*lam; d = nd*lam;
  }
  float ia = a, ic = cc, id = d;
  for (int off = 1; off < 64; off <<= 1) {
    float pa = __shfl_up(ia, off, 64);
    float pc = __shfl_up(ic, off, 64);
    float pd = __shfl_up(id, off, 64);
    if (lane >= off) {
      float na = ia * pa;
      float nc = fmaf(ic, pa, id * pc);
      float nd = id * pd;
      float mx = fmaxf(na, fmaxf(nc, nd));
      float lam = (mx > 0.f) ? (1.0f/mx) : 1.0f;
      ia = na*lam; ic = nc*lam; id = nd*lam;
    }
  }
  if (wid == 0 && lane == 63) {
    float den = fmaf(ic, s0, id);
    float sfin = (den > 0.f) ? (ia * s0)/den : 0.f;
    out[(size_t)2 * Tn * Kn] = logf(sfin + EPSF);
  }
  float ea = __shfl_up(ia, 1, 64);
  float ec = __shfl_up(ic, 1, 64);
  float ed = __shfl_up(id, 1, 64);
  if (lane == 0) { ea = 1.f; ec = 0.f; ed = 1.f; }
  float s;
  { float num = ea * s0; float den = fmaf(ec, s0, ed);
    s = (den > 0.f) ? num/den : 0.f; }
#pragma unroll 4
  for (int i = 0; i < PG; ++i) {
    sArr[lane*PG + i] = s;
    float4 mm = M4[lane*PG + i];
    float num = mm.x * s; float den = fmaf(mm.y, s, mm.z);
    s = (den > 0.f) ? num/den : 0.f;
  }
}

// ============================ scale ============================
// Phase 1: per chunk, serial sigma chain into LDS (u already carries iV, so
// sigma = sn only). Phase 2: coalesced float4 RMW.
__global__ __launch_bounds__(128) void scale3_kernel(float* ws, float* out)
{
  __shared__ float sig[4][Ln3];
  const int tid = threadIdx.x;
  const int g   = tid >> 5;
  const int jj  = tid & 31;
  const bool isF = ((int)blockIdx.x < NBS3);
  const int c = (isF ? (int)blockIdx.x : (int)blockIdx.x - NBS3) * 4 + g;
  constexpr int QPC = Ln3 * Kn / 4;   // 160

  if (isF) {
    const float* mArr = ws + OFF_MF;
    float s = ws[OFF_SF + c];
    const int t0 = c * Ln3;
    for (int i = 0; i < Ln3; ++i) {
      float mm = mArr[t0 + i];
      float z = s * mm;
      float sn = z * FRCP(z + EPSF);
      if (jj == 0) sig[g][i] = sn;
      s = sn;
    }
    __syncthreads();
    float4* A4 = (float4*)out + (size_t)c * QPC;
#pragma unroll
    for (int i = jj; i < QPC; i += 32) {
      int tl = i / 5;
      float sg = sig[g][tl];
      float4 v = A4[i];
      v.x *= sg; v.y *= sg; v.z *= sg; v.w *= sg;
      A4[i] = v;
    }
  } else {
    const float* mArr = ws + OFF_MB;
    const int slot = NC3 - 1 - c;
    float s = ws[OFF_SB + slot];
    const int bodyStart = c * Ln3;
    const int top = bodyStart + Ln3 - 1;
    const bool lastChunk = (c == NC3 - 1);
    for (int r = top; r >= bodyStart; --r) {
      if (r == Tn - 1) {
        if (jj == 0) sig[g][Ln3 - 1] = 1.0f;   // placeholder, overridden below
        continue;
      }
      float mm = mArr[r + 1];
      float z = s * mm;
      float sn = z * FRCP(z + EPSF);
      if (jj == 0) sig[g][r - bodyStart] = sn;
      s = sn;
    }
    __syncthreads();
    float4* B4 = (float4*)out + ((size_t)Tn * Kn) / 4 + (size_t)c * QPC;
#pragma unroll
    for (int i = jj; i < QPC; i += 32) {
      int tl = i / 5;
      if (lastChunk && tl == Ln3 - 1) {
        B4[i] = make_float4(1.f, 1.f, 1.f, 1.f);   // beta[T-1] = ones exactly
      } else {
        float sg = sig[g][tl];
        float4 v = B4[i];
        v.x *= sg; v.y *= sg; v.z *= sg; v.w *= sg;
        B4[i] = v;
      }
    }
  }
}

extern "C" void kernel_launch(void* const* d_in, const int* in_sizes, int n_in,
                              void* d_out, int out_size, void* d_ws, size_t ws_size,
                              hipStream_t stream) {
  const float* obs         = (const float*)d_in[0];
  const float* beta_logits = (const float*)d_in[1];
  const float* pi_logits   = (const float*)d_in[2];
  const float* means       = (const float*)d_in[3];
  const float* log_vars    = (const float*)d_in[4];
  float* out = (float*)d_out;
  float* ws  = (float*)d_ws;   // 23.4 MB used (< proven-available 25.3 MB)

  hipLaunchKernelGGL(prep_kernel, dim3(1), dim3(64), 0, stream,
                     beta_logits, pi_logits, means, log_vars, ws);
  hipLaunchKernelGGL(emis_kernel, dim3(Tn/64), dim3(320), 0, stream, obs, ws);
  hipLaunchKernelGGL(scan3_kernel, dim3(2*NBF), dim3(256), 0, stream, ws, out);
  hipLaunchKernelGGL(combine3_kernel, dim3(1), dim3(128), 0, stream, ws, out);
  hipLaunchKernelGGL(scale3_kernel, dim3(2*NBS3), dim3(128), 0, stream, ws, out);
}

// Round 7
// 90.533 us; speedup vs baseline: 4.8200x; 1.4938x over previous
//
#include <hip/hip_runtime.h>

// HDP-HMM forward-backward, exact-semantics parallel decomposition. R7:
//  - combine kernel parallelized: 1024-thread block per direction, 3-level
//    non-commutative Mobius scan (8 serial/lane -> wave shfl scan -> LDS wave-agg
//    scan) replacing the 2-wave PG=128 serial version that measured 61.7us at
//    0.02% VALUBusy (pure latency, zero occupancy).
//  - scan3/emis/scale3 unchanged from R6.

namespace {
constexpr int Tn = 262144;
constexpr int Kn = 20;
constexpr int Fn = 16;
constexpr float EPSF = 1e-10f;
constexpr float TINY = 1e-35f;

constexpr int Ln3 = 32;
constexpr int Wn3 = 20;
constexpr int NC3 = Tn / Ln3;          // 8192 chunks per direction
constexpr int NBF = NC3 / 16;          // 512 scan blocks per direction
constexpr int NBS3 = NC3 / 4;          // 2048 scale blocks per direction

// ws layout (floats); 23.4 MB
constexpr size_t OFF_P    = 0;
constexpr size_t OFF_W    = 400;
constexpr size_t OFF_CK   = 420;
constexpr size_t OFF_MVIV = 440;
constexpr size_t OFF_E    = 1152;
constexpr size_t OFF_MF   = OFF_E + (size_t)Tn*20 + 64;
constexpr size_t OFF_MB   = OFF_MF + (size_t)Tn;
constexpr size_t OFF_MATF = OFF_MB + (size_t)Tn;
constexpr size_t OFF_MATB = OFF_MATF + 4*(size_t)NC3;
constexpr size_t OFF_SF   = OFF_MATB + 4*(size_t)NC3;
constexpr size_t OFF_SB   = OFF_SF + NC3;
constexpr size_t OFF_END  = OFF_SB + NC3;
}

#if __has_builtin(__builtin_amdgcn_rcpf)
#define FRCP(x) __builtin_amdgcn_rcpf(x)
#else
#define FRCP(x) (1.0f/(x))
#endif

template<int CTRL>
__device__ __forceinline__ float dpp_add(float v) {
  int s = __builtin_amdgcn_update_dpp(0, __float_as_int(v), CTRL, 0xF, 0xF, true);
  return v + __int_as_float(s);
}

// Sum across each 16-lane row, broadcast. Pure DPP.
__device__ __forceinline__ float reduce16(float v) {
  v = dpp_add<0xB1>(v);
  v = dpp_add<0x4E>(v);
  v = dpp_add<0x141>(v);
  v = dpp_add<0x140>(v);
  return v;
}

// ============================ prep ============================
__global__ __launch_bounds__(64) void prep_kernel(
    const float* beta_logits, const float* pi_logits,
    const float* means, const float* log_vars, float* ws)
{
  int k = threadIdx.x;
  if (k < Kn) {
    float row[Kn];
    float mx = -1e30f;
#pragma unroll
    for (int j = 0; j < Kn; ++j) { row[j] = pi_logits[k*Kn + j]; mx = fmaxf(mx, row[j]); }
    float s = 0.f;
#pragma unroll
    for (int j = 0; j < Kn; ++j) { row[j] = expf(row[j] - mx); s += row[j]; }
    float invs = 1.0f / s;
#pragma unroll
    for (int j = 0; j < Kn; ++j) ws[OFF_P + k*Kn + j] = row[j] * invs;
    float ck = 0.f;
#pragma unroll
    for (int f = 0; f < Fn; ++f) {
      float lv  = log_vars[k*Fn + f];
      float var = expf(lv) + 1e-6f;
      float iv  = 1.0f / var;
      float mu  = means[k*Fn + f];
      ((float2*)(ws + OFF_MVIV))[k*Fn + f] = make_float2(mu * iv, iv);
      ck += mu*mu*iv + logf(6.2831853071795864f * var);
    }
    ws[OFF_CK + k] = ck;
  } else if (k == Kn) {
    float cp = 1.f;
#pragma unroll
    for (int i = 0; i < Kn; ++i) {
      float b = 1.0f / (1.0f + expf(-beta_logits[i]));
      ws[OFF_W + i] = b * cp;
      cp *= (1.0f - b);
    }
  }
}

// ============================ emission ============================
__global__ __launch_bounds__(320) void emis_kernel(const float* __restrict__ obs, float* ws)
{
  __shared__ __align__(16) float so[64][20];
  __shared__ __align__(16) float scm[16][24];
  __shared__ __align__(16) float scv[16][24];
  __shared__ __align__(16) float sck[20];
  const int tid = threadIdx.x;
  const int t0 = blockIdx.x * 64;

  if (tid < 256) {
    float4 v = ((const float4*)(obs + (size_t)t0 * Fn))[tid];
    int r = tid >> 2, j = tid & 3;
    *(float4*)&so[r][j*4] = v;
  } else {
    int i = tid - 256;
#pragma unroll
    for (int q = 0; q < 5; ++q) {
      int idx = i * 5 + q;
      float2 c2 = ((const float2*)(ws + OFF_MVIV))[idx];
      int k = idx >> 4, f = idx & 15;
      scm[f][k] = c2.x;
      scv[f][k] = c2.y;
    }
    if (i < Kn) sck[i] = ws[OFF_CK + i];
  }
  __syncthreads();

  const int tl = tid / 5;
  const int k0 = (tid - tl*5) * 4;

  float o[16];
  *(float4*)&o[0]  = *(const float4*)&so[tl][0];
  *(float4*)&o[4]  = *(const float4*)&so[tl][4];
  *(float4*)&o[8]  = *(const float4*)&so[tl][8];
  *(float4*)&o[12] = *(const float4*)&so[tl][12];

  float s1x=0.f,s1y=0.f,s1z=0.f,s1w=0.f;
  float s2x=0.f,s2y=0.f,s2z=0.f,s2w=0.f;
#pragma unroll
  for (int f = 0; f < Fn; ++f) {
    float4 cm = *(const float4*)&scm[f][k0];
    float4 cv = *(const float4*)&scv[f][k0];
    float ov = o[f];
    s1x = fmaf(cv.x * ov, ov, s1x); s2x = fmaf(cm.x, ov, s2x);
    s1y = fmaf(cv.y * ov, ov, s1y); s2y = fmaf(cm.y, ov, s2y);
    s1z = fmaf(cv.z * ov, ov, s1z); s2z = fmaf(cm.z, ov, s2z);
    s1w = fmaf(cv.w * ov, ov, s1w); s2w = fmaf(cm.w, ov, s2w);
  }
  float4 ckv = *(const float4*)&sck[k0];
  float4 rr;
  rr.x = __expf(fmaf(-0.5f, s1x + ckv.x, s2x));
  rr.y = __expf(fmaf(-0.5f, s1y + ckv.y, s2y));
  rr.z = __expf(fmaf(-0.5f, s1z + ckv.z, s2z));
  rr.w = __expf(fmaf(-0.5f, s1w + ckv.w, s2w));
  *(float4*)(ws + OFF_E + (size_t)(t0 + tl)*20 + k0) = rr;
}

// ============================ scan ============================
__global__ __launch_bounds__(256, 4) void scan3_kernel(float* ws, float* out)
{
  __shared__ __align__(16) float xsh[16][20];
  const int tid = threadIdx.x;
  const int g   = tid >> 4;
  const int ll  = tid & 15;
  const bool hi = (ll < 4);
  const int l4  = 16 + (ll & 3);
  const bool isF = ((int)blockIdx.x < NBF);
  const int c = (isF ? (int)blockIdx.x : (int)blockIdx.x - NBF) * 16 + g;
  const float* E = ws + OFF_E;
  float* xg = &xsh[g][0];

  float Pv0[Kn], Pv1[Kn];
#pragma unroll
  for (int k = 0; k < Kn; ++k) {
    if (isF) {
      Pv0[k] = ws[OFF_P + k*Kn + ll];
      float p1 = ws[OFF_P + k*Kn + l4];
      Pv1[k] = hi ? p1 : 0.f;
    } else {
      Pv0[k] = ws[OFF_P + ll*Kn + k];
      float p1 = ws[OFF_P + l4*Kn + k];
      Pv1[k] = hi ? p1 : 0.f;
    }
  }

  float Ma = 1.f, Mc = 0.f, Md = 1.f;
  float* mArr = ws + (isF ? OFF_MF : OFF_MB);
  float* uOut = out + (isF ? (size_t)0 : (size_t)Tn * Kn);

  auto mobius = [&](float m) {
    float na = m * Ma;
    float nc = fmaf(EPSF, Mc, na);
    float nd = EPSF * Md;
    float mx = fmaxf(nc, nd);
    float lam = (mx > 0.f) ? FRCP(mx) : 1.0f;
    Ma = na*lam; Mc = nc*lam; Md = nd*lam;
  };
  auto matvec2 = [&](float& r0, float& r1) {
    float xv[20];
    *(float4*)&xv[0]  = *(const float4*)&xg[0];
    *(float4*)&xv[4]  = *(const float4*)&xg[4];
    *(float4*)&xv[8]  = *(const float4*)&xg[8];
    *(float4*)&xv[12] = *(const float4*)&xg[12];
    *(float4*)&xv[16] = *(const float4*)&xg[16];
    float A0 = xv[0]*Pv0[0], A1 = xv[1]*Pv0[1];
    float B0 = xv[0]*Pv1[0], B1 = xv[1]*Pv1[1];
#pragma unroll
    for (int k = 2; k < 20; k += 2) {
      A0 = fmaf(xv[k],   Pv0[k],   A0);
      A1 = fmaf(xv[k+1], Pv0[k+1], A1);
      B0 = fmaf(xv[k],   Pv1[k],   B0);
      B1 = fmaf(xv[k+1], Pv1[k+1], B1);
    }
    r0 = A0 + A1; r1 = B0 + B1;
  };

  if (isF) {
    const int bodyStart = c * Ln3;
    const int tend = bodyStart + Ln3 - 1;
    const int t0 = (c == 0) ? 0 : (bodyStart - Wn3);
    float e0a = E[t0*20 + ll],     e1a = E[t0*20 + l4];
    float v0, v1;
    if (c == 0) {
      v0 = ws[OFF_W + ll] * e0a;
      v1 = hi ? ws[OFF_W + l4] * e1a : 0.f;
    } else {
      v0 = 0.05f * e0a;
      v1 = hi ? 0.05f * e1a : 0.f;
    }
    float sv = reduce16(v0 + v1);
    float m = sv;
    float iV = (sv > TINY) ? FRCP(sv) : 1.0f;
    if (sv <= TINY) { v0 = 0.05f; v1 = hi ? 0.05f : 0.f; }
    if (c == 0) {
      if (ll == 0) mArr[0] = m;
      mobius(m);
      uOut[ll] = v0 * iV;
      if (hi) uOut[l4] = v1 * iV;
    }
    float A = m * iV;
    float rho = (m > TINY) ? FRCP(m) : 1.0f;
    float e0b = E[(t0+1)*20 + ll], e1b = E[(t0+1)*20 + l4];
    float e0c = E[(t0+2)*20 + ll], e1c = E[(t0+2)*20 + l4];

#define FWD_STEP(REC)                                                     \
    {                                                                     \
      xg[ll] = v0;                                                        \
      if (hi) xg[16 + ll] = v1;                                           \
      float acc0, acc1; matvec2(acc0, acc1);                              \
      float er0 = e0a * rho, er1 = e1a * rho;                             \
      e0a = e0b; e0b = e0c; e0c = E[(t+3)*20 + ll];                       \
      e1a = e1b; e1b = e1c; e1c = E[(t+3)*20 + l4];                       \
      v0 = acc0 * er0; v1 = acc1 * er1;                                   \
      float sv2 = reduce16(v0 + v1);                                      \
      float mn = sv2 * A;                                                 \
      float iVn = (sv2 > TINY) ? FRCP(sv2) : 1.0f;                        \
      if (sv2 <= TINY) { v0 = 0.05f; v1 = hi ? 0.05f : 0.f; }             \
      if (REC) {                                                          \
        if (ll == 0) mArr[t] = mn;                                        \
        mobius(mn);                                                       \
        uOut[(size_t)t*Kn + ll] = v0 * iVn;                               \
        if (hi) uOut[(size_t)t*Kn + 16 + ll] = v1 * iVn;                  \
      }                                                                   \
      A = mn * iVn;                                                       \
      rho = (mn > TINY) ? FRCP(mn) : 1.0f;                                \
    }

    for (int t = t0 + 1; t < bodyStart; ++t) FWD_STEP(false)
    const int bstart2 = (c == 0) ? 1 : bodyStart;
    for (int t = bstart2; t <= tend; ++t) FWD_STEP(true)
#undef FWD_STEP
    if (ll == 0) ((float4*)(ws + OFF_MATF))[c] = make_float4(Ma, Mc, Md, 0.f);
  } else {
    const int bodyStart = c * Ln3;
    const int top = bodyStart + Ln3 - 1;
    int r0 = top + Wn3; if (r0 > Tn - 1) r0 = Tn - 1;
    float v0 = 0.05f, v1 = hi ? 0.05f : 0.f;
    float sv = reduce16(v0 + v1);
    float iV = (sv > TINY) ? FRCP(sv) : 1.0f;
    float A = iV;
    float rho = 1.0f;
    float e0a = E[r0*20 + ll],     e1a = E[r0*20 + l4];
    float e0b = E[(r0-1)*20 + ll], e1b = E[(r0-1)*20 + l4];
    float e0c = E[(r0-2)*20 + ll], e1c = E[(r0-2)*20 + l4];

#define BWD_STEP(REC)                                                     \
    {                                                                     \
      xg[ll] = v0 * e0a;                                                  \
      if (hi) xg[16 + ll] = v1 * e1a;                                     \
      float acc0, acc1; matvec2(acc0, acc1);                              \
      v0 = acc0 * rho; v1 = acc1 * rho;                                   \
      e0a = e0b; e0b = e0c; e0c = E[(r-2)*20 + ll];                       \
      e1a = e1b; e1b = e1c; e1c = E[(r-2)*20 + l4];                       \
      float sv2 = reduce16(v0 + v1);                                      \
      float mn = sv2 * A;                                                 \
      float iVn = (sv2 > TINY) ? FRCP(sv2) : 1.0f;                        \
      if (sv2 <= TINY) { v0 = 0.05f; v1 = hi ? 0.05f : 0.f; }             \
      if (REC) {                                                          \
        if (ll == 0) mArr[r+1] = mn;                                      \
        mobius(mn);                                                       \
        uOut[(size_t)r*Kn + ll] = v0 * iVn;                               \
        if (hi) uOut[(size_t)r*Kn + 16 + ll] = v1 * iVn;                  \
      }                                                                   \
      A = mn * iVn;                                                       \
      rho = (mn > TINY) ? FRCP(mn) : 1.0f;                                \
    }

    for (int r = r0 - 1; r > top; --r) BWD_STEP(false)
    int rb = (r0 - 1 < top) ? (r0 - 1) : top;
    for (int r = rb; r >= bodyStart; --r) BWD_STEP(true)
#undef BWD_STEP
    if (ll == 0) ((float4*)(ws + OFF_MATB))[NC3 - 1 - c] = make_float4(Ma, Mc, Md, 0.f);
  }
}

// ============================ combine ============================
// 1024 threads per direction; PG=8 maps per thread. 3-level non-commutative scan:
// per-thread serial compose -> wave shfl_up scan -> LDS scan of 16 wave aggregates.
__global__ __launch_bounds__(1024) void combine4_kernel(float* ws, float* out)
{
  __shared__ float wag[16][3];
  __shared__ float wpre[16][3];
  const bool isF = (blockIdx.x == 0);
  const float4* M4 = (const float4*)(ws + (isF ? OFF_MATF : OFF_MATB));
  float* sArr = ws + (isF ? OFF_SF : OFF_SB);
  const float s0 = isF ? 1.0f : 20.0f;
  constexpr int PG = NC3 / 1024;   // 8
  const int tid  = threadIdx.x;
  const int lane = tid & 63;
  const int wid  = tid >> 6;       // 0..15

  float4 mm[PG];
#pragma unroll
  for (int i = 0; i < PG; ++i) mm[i] = M4[tid*PG + i];

  // per-thread serial composite (apply mm[0] first)
  float a = 1.f, cc = 0.f, d = 1.f;
#pragma unroll
  for (int i = 0; i < PG; ++i) {
    float na = mm[i].x * a;
    float nc = fmaf(mm[i].y, a, mm[i].z * cc);
    float nd = mm[i].z * d;
    float mx = fmaxf(na, fmaxf(nc, nd));
    float lam = (mx > 0.f) ? FRCP(mx) : 1.0f;
    a = na*lam; cc = nc*lam; d = nd*lam;
  }

  // inclusive wave scan (compose after lower lanes)
  float ia = a, ic = cc, id = d;
  for (int off = 1; off < 64; off <<= 1) {
    float pa = __shfl_up(ia, off, 64);
    float pc = __shfl_up(ic, off, 64);
    float pd = __shfl_up(id, off, 64);
    if (lane >= off) {
      float na = ia * pa;
      float nc = fmaf(ic, pa, id * pc);
      float nd = id * pd;
      float mx = fmaxf(na, fmaxf(nc, nd));
      float lam = (mx > 0.f) ? FRCP(mx) : 1.0f;
      ia = na*lam; ic = nc*lam; id = nd*lam;
    }
  }
  if (lane == 63) { wag[wid][0] = ia; wag[wid][1] = ic; wag[wid][2] = id; }
  __syncthreads();

  // thread 0: serial exclusive scan over the 16 wave aggregates
  if (tid == 0) {
    float ea = 1.f, ec = 0.f, ed = 1.f;
#pragma unroll
    for (int w = 0; w < 16; ++w) {
      wpre[w][0] = ea; wpre[w][1] = ec; wpre[w][2] = ed;
      float na = wag[w][0] * ea;
      float nc = fmaf(wag[w][1], ea, wag[w][2] * ec);
      float nd = wag[w][2] * ed;
      float mx = fmaxf(na, fmaxf(nc, nd));
      float lam = (mx > 0.f) ? FRCP(mx) : 1.0f;
      ea = na*lam; ec = nc*lam; ed = nd*lam;
    }
    if (isF) {   // full-sequence composite -> log-likelihood
      float den = fmaf(ec, s0, ed);
      float sfin = (den > 0.f) ? (ea * s0)/den : 0.f;
      out[(size_t)2 * Tn * Kn] = logf(sfin + EPSF);
    }
  }
  __syncthreads();

  // exclusive per-thread prefix = (lane-exclusive within wave) ∘ wave prefix
  float ea = __shfl_up(ia, 1, 64);
  float ec = __shfl_up(ic, 1, 64);
  float ed = __shfl_up(id, 1, 64);
  if (lane == 0) { ea = 1.f; ec = 0.f; ed = 1.f; }
  float pa = wpre[wid][0], pc = wpre[wid][1], pd = wpre[wid][2];
  float xa = ea * pa;
  float xc = fmaf(ec, pa, ed * pc);
  float xd = ed * pd;

  // s entering my 8-chunk segment, then replay
  float num = xa * s0, den = fmaf(xc, s0, xd);
  float s = (den > 0.f) ? num/den : 0.f;
#pragma unroll
  for (int i = 0; i < PG; ++i) {
    sArr[tid*PG + i] = s;
    float nn = mm[i].x * s, dd = fmaf(mm[i].y, s, mm[i].z);
    s = (dd > 0.f) ? nn/dd : 0.f;
  }
}

// ============================ scale ============================
__global__ __launch_bounds__(128) void scale3_kernel(float* ws, float* out)
{
  __shared__ float sig[4][Ln3];
  const int tid = threadIdx.x;
  const int g   = tid >> 5;
  const int jj  = tid & 31;
  const bool isF = ((int)blockIdx.x < NBS3);
  const int c = (isF ? (int)blockIdx.x : (int)blockIdx.x - NBS3) * 4 + g;
  constexpr int QPC = Ln3 * Kn / 4;   // 160

  if (isF) {
    const float* mArr = ws + OFF_MF;
    float s = ws[OFF_SF + c];
    const int t0 = c * Ln3;
    for (int i = 0; i < Ln3; ++i) {
      float mm = mArr[t0 + i];
      float z = s * mm;
      float sn = z * FRCP(z + EPSF);
      if (jj == 0) sig[g][i] = sn;
      s = sn;
    }
    __syncthreads();
    float4* A4 = (float4*)out + (size_t)c * QPC;
#pragma unroll
    for (int i = jj; i < QPC; i += 32) {
      int tl = i / 5;
      float sg = sig[g][tl];
      float4 v = A4[i];
      v.x *= sg; v.y *= sg; v.z *= sg; v.w *= sg;
      A4[i] = v;
    }
  } else {
    const float* mArr = ws + OFF_MB;
    const int slot = NC3 - 1 - c;
    float s = ws[OFF_SB + slot];
    const int bodyStart = c * Ln3;
    const int top = bodyStart + Ln3 - 1;
    const bool lastChunk = (c == NC3 - 1);
    for (int r = top; r >= bodyStart; --r) {
      if (r == Tn - 1) {
        if (jj == 0) sig[g][Ln3 - 1] = 1.0f;
        continue;
      }
      float mm = mArr[r + 1];
      float z = s * mm;
      float sn = z * FRCP(z + EPSF);
      if (jj == 0) sig[g][r - bodyStart] = sn;
      s = sn;
    }
    __syncthreads();
    float4* B4 = (float4*)out + ((size_t)Tn * Kn) / 4 + (size_t)c * QPC;
#pragma unroll
    for (int i = jj; i < QPC; i += 32) {
      int tl = i / 5;
      if (lastChunk && tl == Ln3 - 1) {
        B4[i] = make_float4(1.f, 1.f, 1.f, 1.f);
      } else {
        float sg = sig[g][tl];
        float4 v = B4[i];
        v.x *= sg; v.y *= sg; v.z *= sg; v.w *= sg;
        B4[i] = v;
      }
    }
  }
}

extern "C" void kernel_launch(void* const* d_in, const int* in_sizes, int n_in,
                              void* d_out, int out_size, void* d_ws, size_t ws_size,
                              hipStream_t stream) {
  const float* obs         = (const float*)d_in[0];
  const float* beta_logits = (const float*)d_in[1];
  const float* pi_logits   = (const float*)d_in[2];
  const float* means       = (const float*)d_in[3];
  const float* log_vars    = (const float*)d_in[4];
  float* out = (float*)d_out;
  float* ws  = (float*)d_ws;

  hipLaunchKernelGGL(prep_kernel, dim3(1), dim3(64), 0, stream,
                     beta_logits, pi_logits, means, log_vars, ws);
  hipLaunchKernelGGL(emis_kernel, dim3(Tn/64), dim3(320), 0, stream, obs, ws);
  hipLaunchKernelGGL(scan3_kernel, dim3(2*NBF), dim3(256), 0, stream, ws, out);
  hipLaunchKernelGGL(combine4_kernel, dim3(2), dim3(1024), 0, stream, ws, out);
  hipLaunchKernelGGL(scale3_kernel, dim3(2*NBS3), dim3(128), 0, stream, ws, out);
}